// Round 1
// baseline (5353.572 us; speedup 1.0000x reference)
//
#include <hip/hip_runtime.h>
#include <hip/hip_bf16.h>
#include <stdint.h>

// ---------------- problem constants ----------------
#define B_    2
#define S_    2048
#define H_    16
#define DM    2048
#define QL    1536
#define KVL   512
#define NOPE_ 128
#define ROPE_ 64
#define DQK   192
#define DV    128
#define DFF   8192
#define NT    (B_ * S_)          // 4096 token rows
#define EPS_  1e-5f

typedef __bf16 bf16x8 __attribute__((ext_vector_type(8)));
typedef float  f32x4  __attribute__((ext_vector_type(4)));

__device__ __forceinline__ unsigned short f2bf(float f) {
  union { float f; uint32_t u; } v; v.f = f;
  uint32_t r = v.u + 0x7fffu + ((v.u >> 16) & 1u);
  return (unsigned short)(r >> 16);
}
__device__ __forceinline__ float bf2f(unsigned short h) {
  union { uint32_t u; float f; } v; v.u = ((uint32_t)h) << 16;
  return v.f;
}
__device__ __forceinline__ float ldv(float x) { return x; }
__device__ __forceinline__ float ldv(unsigned short x) { return bf2f(x); }

// ---------------- weight transpose + bf16 convert: W(K,N) f32 -> Wt(N,K) bf16 ----------------
__global__ __launch_bounds__(256) void wt_kernel(const float* __restrict__ W,
                                                 unsigned short* __restrict__ Wt,
                                                 int K, int N) {
  __shared__ unsigned short tile[32][33];
  int kt = blockIdx.y * 32, nt = blockIdx.x * 32;
  int tx = threadIdx.x & 31, ty = threadIdx.x >> 5;   // ty 0..7
#pragma unroll
  for (int kk = 0; kk < 32; kk += 8)
    tile[kk + ty][tx] = f2bf(W[(size_t)(kt + kk + ty) * N + nt + tx]);   // coalesced in n
  __syncthreads();
#pragma unroll
  for (int nn = 0; nn < 32; nn += 8)
    Wt[(size_t)(nt + nn + ty) * K + kt + tx] = tile[tx][nn + ty];        // coalesced in k
}

// ---------------- RMSNorm: rows x D (row stride ldin), optional weight, out bf16 ----------------
template <typename TIN>
__global__ __launch_bounds__(256) void rms_kernel(const TIN* __restrict__ in,
                                                  unsigned short* __restrict__ out,
                                                  const float* __restrict__ w,
                                                  int D, int ldin) {
  int row = blockIdx.x, tid = threadIdx.x;
  const TIN* rp = in + (size_t)row * ldin;
  float ss = 0.f;
  for (int i = tid; i < D; i += 256) { float v = ldv(rp[i]); ss += v * v; }
#pragma unroll
  for (int off = 32; off >= 1; off >>= 1) ss += __shfl_xor(ss, off);
  __shared__ float red[4];
  if ((tid & 63) == 0) red[tid >> 6] = ss;
  __syncthreads();
  ss = red[0] + red[1] + red[2] + red[3];
  float rs = rsqrtf(ss / (float)D + EPS_);
  unsigned short* op = out + (size_t)row * D;
  for (int i = tid; i < D; i += 256) {
    float v = ldv(rp[i]) * rs;
    if (w) v *= w[i];
    op[i] = f2bf(v);
  }
}

// ---------------- generic bf16 MFMA GEMM: C(M,N) = A(M,K) @ Bt(N,K)^T ----------------
// block 256 = 4 waves, block tile 64x64, wave tile 16x64
// MODE 0: store bf16   MODE 1: store f32   MODE 2: store f32 = addsrc + acc
template <int MODE>
__global__ __launch_bounds__(256) void gemm_kernel(const unsigned short* __restrict__ A,
                                                   const unsigned short* __restrict__ Bt,
                                                   void* C, const float* addsrc,
                                                   int M, int N, int K) {
  int lane = threadIdx.x & 63, wave = threadIdx.x >> 6;
  int quad = lane >> 4, l16 = lane & 15;
  int row0 = blockIdx.y * 64 + wave * 16;
  int col0 = blockIdx.x * 64;
  const unsigned short* Ap = A + (size_t)(row0 + l16) * K + quad * 8;
  const unsigned short* Bp = Bt + (size_t)(col0 + l16) * K + quad * 8;
  size_t bs16 = (size_t)16 * K;
  f32x4 ac[4] = {};
  for (int k = 0; k < K; k += 32) {
    bf16x8 a = *(const bf16x8*)(Ap + k);
#pragma unroll
    for (int t = 0; t < 4; ++t) {
      bf16x8 b = *(const bf16x8*)(Bp + bs16 * t + k);
      ac[t] = __builtin_amdgcn_mfma_f32_16x16x32_bf16(a, b, ac[t], 0, 0, 0);
    }
  }
#pragma unroll
  for (int t = 0; t < 4; ++t)
#pragma unroll
    for (int r = 0; r < 4; ++r) {
      int row = row0 + quad * 4 + r, col = col0 + t * 16 + l16;
      size_t idx = (size_t)row * N + col;
      float v = ac[t][r];
      if (MODE == 0)      ((unsigned short*)C)[idx] = f2bf(v);
      else if (MODE == 1) ((float*)C)[idx] = v;
      else                ((float*)C)[idx] = addsrc[idx] + v;
    }
}

// ---------------- fused gate/up GEMM + SiLU: M = silu(A@Wg) * (A@Wu), bf16 out ----------------
__global__ __launch_bounds__(256) void gemm_gateup_kernel(const unsigned short* __restrict__ A,
                                                          const unsigned short* __restrict__ Bg,
                                                          const unsigned short* __restrict__ Bu,
                                                          unsigned short* __restrict__ Mo,
                                                          int M, int N, int K) {
  int lane = threadIdx.x & 63, wave = threadIdx.x >> 6;
  int quad = lane >> 4, l16 = lane & 15;
  int row0 = blockIdx.y * 64 + wave * 16;
  int col0 = blockIdx.x * 64;
  const unsigned short* Ap = A + (size_t)(row0 + l16) * K + quad * 8;
  const unsigned short* Bgp = Bg + (size_t)(col0 + l16) * K + quad * 8;
  const unsigned short* Bup = Bu + (size_t)(col0 + l16) * K + quad * 8;
  size_t bs16 = (size_t)16 * K;
  f32x4 ag[4] = {}, au[4] = {};
  for (int k = 0; k < K; k += 32) {
    bf16x8 a = *(const bf16x8*)(Ap + k);
#pragma unroll
    for (int t = 0; t < 4; ++t) {
      bf16x8 bg = *(const bf16x8*)(Bgp + bs16 * t + k);
      ag[t] = __builtin_amdgcn_mfma_f32_16x16x32_bf16(a, bg, ag[t], 0, 0, 0);
      bf16x8 bu = *(const bf16x8*)(Bup + bs16 * t + k);
      au[t] = __builtin_amdgcn_mfma_f32_16x16x32_bf16(a, bu, au[t], 0, 0, 0);
    }
  }
#pragma unroll
  for (int t = 0; t < 4; ++t)
#pragma unroll
    for (int r = 0; r < 4; ++r) {
      int row = row0 + quad * 4 + r, col = col0 + t * 16 + l16;
      float g = ag[t][r], u = au[t][r];
      float s = g / (1.f + __expf(-g));
      Mo[(size_t)row * N + col] = f2bf(s * u);
    }
}

// ---------------- build Q with RoPE: qg(NT, H*192 bf16) -> qo(NT,H,192) = [rope(64)|nope(128)] ----------------
__global__ __launch_bounds__(256) void build_q_kernel(const unsigned short* __restrict__ qg,
                                                      const float* __restrict__ fcos,
                                                      const float* __restrict__ fsin,
                                                      unsigned short* __restrict__ qo) {
  int idx = blockIdx.x * 256 + threadIdx.x;
  if (idx >= NT * H_ * 96) return;
  int i = idx % 96, t = idx / 96;
  int h = t % H_, bs = t / H_, s = bs % S_;
  const unsigned short* src = qg + (size_t)bs * (H_ * DQK) + h * DQK;
  unsigned short* dst = qo + ((size_t)bs * H_ + h) * DQK;
  if (i < 32) {
    float xr = bf2f(src[NOPE_ + 2 * i]), xi = bf2f(src[NOPE_ + 2 * i + 1]);
    float c = fcos[s * 32 + i], sn = fsin[s * 32 + i];
    dst[2 * i]     = f2bf(xr * c - xi * sn);
    dst[2 * i + 1] = f2bf(xr * sn + xi * c);
  } else {
    int j = i - 32;
    dst[ROPE_ + 2 * j]     = src[2 * j];
    dst[ROPE_ + 2 * j + 1] = src[2 * j + 1];
  }
}

// ---------------- build K: rope(kv_lr[:,512:576]) broadcast + k_nope from kv ----------------
__global__ __launch_bounds__(256) void build_k_kernel(const float* __restrict__ kvlr,
                                                      const unsigned short* __restrict__ kv,
                                                      const float* __restrict__ fcos,
                                                      const float* __restrict__ fsin,
                                                      unsigned short* __restrict__ ko) {
  int idx = blockIdx.x * 256 + threadIdx.x;
  if (idx >= NT * H_ * 96) return;
  int i = idx % 96, t = idx / 96;
  int h = t % H_, bs = t / H_, s = bs % S_;
  unsigned short* dst = ko + ((size_t)bs * H_ + h) * DQK;
  if (i < 32) {
    float xr = kvlr[(size_t)bs * (KVL + ROPE_) + KVL + 2 * i];
    float xi = kvlr[(size_t)bs * (KVL + ROPE_) + KVL + 2 * i + 1];
    float c = fcos[s * 32 + i], sn = fsin[s * 32 + i];
    dst[2 * i]     = f2bf(xr * c - xi * sn);
    dst[2 * i + 1] = f2bf(xr * sn + xi * c);
  } else {
    int j = i - 32;
    dst[ROPE_ + 2 * j]     = kv[(size_t)bs * 4096 + h * DV + 2 * j];
    dst[ROPE_ + 2 * j + 1] = kv[(size_t)bs * 4096 + h * DV + 2 * j + 1];
  }
}

// ---------------- flash attention: Br=64 (4 waves x 16 rows), Bc=32, MFMA QK^T and PV ----------------
__global__ __launch_bounds__(256) void attn_kernel(const unsigned short* __restrict__ Q,
                                                   const unsigned short* __restrict__ Kt,
                                                   const unsigned short* __restrict__ KV,
                                                   const int* __restrict__ smaskg,
                                                   unsigned short* __restrict__ O) {
  __shared__ unsigned short Qs[64 * DQK];   // 24576 B
  __shared__ unsigned short Ks[32 * DQK];   // 12288 B
  __shared__ unsigned short Vts[DV * 32];   // 8192 B (transposed: d-major, key-contiguous)
  __shared__ unsigned short Ps[4][16 * 32]; // per-wave P tile, bf16
  __shared__ int smask[32];

  const float SCALE = 0.07216878364870323f; // 1/sqrt(192)
  int tid = threadIdx.x, wave = tid >> 6, lane = tid & 63;
  int quad = lane >> 4, l16 = lane & 15;
  int bh = blockIdx.y, b = bh / H_, h = bh % H_;
  int r0 = blockIdx.x * 64;

  // stage Q tile (16B chunks)
  size_t qbase = ((size_t)(b * S_ + r0) * H_ + h) * DQK;
  for (int i = tid; i < 64 * DQK / 8; i += 256) {
    int row = i / 24, dd = (i % 24) * 8;
    *(uint4*)(Qs + row * DQK + dd) = *(const uint4*)(Q + qbase + (size_t)row * H_ * DQK + dd);
  }

  float m_[4] = {-3e38f, -3e38f, -3e38f, -3e38f};
  float l_[4] = {0.f, 0.f, 0.f, 0.f};
  f32x4 o_[8] = {};

  int ktend = (r0 + 64) / 32;
  for (int kt = 0; kt < ktend; ++kt) {
    int j0 = kt * 32;
    __syncthreads();
    size_t kbase = ((size_t)(b * S_ + j0) * H_ + h) * DQK;
    for (int i = tid; i < 32 * DQK / 8; i += 256) {
      int row = i / 24, dd = (i % 24) * 8;
      *(uint4*)(Ks + row * DQK + dd) = *(const uint4*)(Kt + kbase + (size_t)row * H_ * DQK + dd);
    }
    size_t vbase = (size_t)(b * S_ + j0) * 4096 + H_ * NOPE_ + h * DV;
    for (int i = tid; i < 32 * DV; i += 256) {
      int key = i >> 7, dd = i & 127;
      Vts[dd * 32 + key] = KV[vbase + (size_t)key * 4096 + dd];
    }
    if (tid < 32) smask[tid] = smaskg[b * S_ + j0 + tid];
    __syncthreads();

    // S = Q K^T  (wave w: rows r0+16w .. +15; cols j0..j0+31 in two 16-col tiles)
    f32x4 sc0 = {0.f, 0.f, 0.f, 0.f}, sc1 = {0.f, 0.f, 0.f, 0.f};
    const unsigned short* qrow  = Qs + (wave * 16 + l16) * DQK + quad * 8;
    const unsigned short* krow0 = Ks + l16 * DQK + quad * 8;
    const unsigned short* krow1 = Ks + (16 + l16) * DQK + quad * 8;
#pragma unroll
    for (int kk = 0; kk < DQK; kk += 32) {
      bf16x8 a = *(const bf16x8*)(qrow + kk);
      sc0 = __builtin_amdgcn_mfma_f32_16x16x32_bf16(a, *(const bf16x8*)(krow0 + kk), sc0, 0, 0, 0);
      sc1 = __builtin_amdgcn_mfma_f32_16x16x32_bf16(a, *(const bf16x8*)(krow1 + kk), sc1, 0, 0, 0);
    }

    int rowg_base = r0 + wave * 16 + quad * 4;
    bool ok0 = smask[l16] != 0, ok1 = smask[16 + l16] != 0;
    float s0[4], s1[4];
#pragma unroll
    for (int r = 0; r < 4; ++r) {
      int rg = rowg_base + r;
      s0[r] = (ok0 && (j0 + l16) <= rg)      ? sc0[r] * SCALE : -1e30f;
      s1[r] = (ok1 && (j0 + 16 + l16) <= rg) ? sc1[r] * SCALE : -1e30f;
    }
#pragma unroll
    for (int r = 0; r < 4; ++r) {
      float tm = fmaxf(s0[r], s1[r]);
      tm = fmaxf(tm, __shfl_xor(tm, 1));
      tm = fmaxf(tm, __shfl_xor(tm, 2));
      tm = fmaxf(tm, __shfl_xor(tm, 4));
      tm = fmaxf(tm, __shfl_xor(tm, 8));
      float mn = fmaxf(m_[r], tm);
      float al = __expf(m_[r] - mn);
      m_[r] = mn;
      float p0 = __expf(s0[r] - mn);
      float p1 = __expf(s1[r] - mn);
      float ps = p0 + p1;
      ps += __shfl_xor(ps, 1);
      ps += __shfl_xor(ps, 2);
      ps += __shfl_xor(ps, 4);
      ps += __shfl_xor(ps, 8);
      l_[r] = l_[r] * al + ps;
#pragma unroll
      for (int nt = 0; nt < 8; ++nt) o_[nt][r] *= al;
      Ps[wave][(quad * 4 + r) * 32 + l16]      = f2bf(p0);
      Ps[wave][(quad * 4 + r) * 32 + 16 + l16] = f2bf(p1);
    }

    // O += P V   (P: A-operand layout via LDS round-trip; V transposed in LDS)
    bf16x8 pa = *(const bf16x8*)(&Ps[wave][l16 * 32 + quad * 8]);
#pragma unroll
    for (int nt = 0; nt < 8; ++nt) {
      bf16x8 vb = *(const bf16x8*)(&Vts[(nt * 16 + l16) * 32 + quad * 8]);
      o_[nt] = __builtin_amdgcn_mfma_f32_16x16x32_bf16(pa, vb, o_[nt], 0, 0, 0);
    }
  }

  // epilogue: O layout (B,S,H*DV)
#pragma unroll
  for (int nt = 0; nt < 8; ++nt)
#pragma unroll
    for (int r = 0; r < 4; ++r) {
      int rg = r0 + wave * 16 + quad * 4 + r;
      float v = o_[nt][r] / l_[r];
      O[((size_t)(b * S_ + rg) * H_ + h) * DV + nt * 16 + l16] = f2bf(v);
    }
}

// ---------------- host launch ----------------
extern "C" void kernel_launch(void* const* d_in, const int* in_sizes, int n_in,
                              void* d_out, int out_size, void* d_ws, size_t ws_size,
                              hipStream_t stream) {
  const float* hidden  = (const float*)d_in[0];
  const int*   seqmask = (const int*)d_in[1];
  const float* fcos    = (const float*)d_in[2];
  const float* fsin    = (const float*)d_in[3];
  const float* ln1     = (const float*)d_in[4];
  const float* ln2     = (const float*)d_in[5];
  const float* Wqd     = (const float*)d_in[6];
  const float* Wqu     = (const float*)d_in[7];
  const float* Wkvd    = (const float*)d_in[8];
  const float* Wkvu    = (const float*)d_in[9];
  const float* Wo      = (const float*)d_in[10];
  const float* Wg      = (const float*)d_in[11];
  const float* Wu      = (const float*)d_in[12];
  const float* Wd      = (const float*)d_in[13];
  float* out = (float*)d_out;
  char* ws = (char*)d_ws;

  // weight arena (bf16, transposed N x K)
  size_t off = 0;
  unsigned short* Wqd_t  = (unsigned short*)(ws + off); off += (size_t)QL * DM * 2;
  unsigned short* Wqu_t  = (unsigned short*)(ws + off); off += (size_t)(H_ * DQK) * QL * 2;
  unsigned short* Wkvd_t = (unsigned short*)(ws + off); off += (size_t)(KVL + ROPE_) * DM * 2;
  unsigned short* Wkvu_t = (unsigned short*)(ws + off); off += (size_t)4096 * KVL * 2;
  unsigned short* Wo_t   = (unsigned short*)(ws + off); off += (size_t)DM * DM * 2;
  unsigned short* Wg_t   = (unsigned short*)(ws + off); off += (size_t)DFF * DM * 2;
  unsigned short* Wu_t   = (unsigned short*)(ws + off); off += (size_t)DFF * DM * 2;
  unsigned short* Wd_t   = (unsigned short*)(ws + off); off += (size_t)DM * DFF * 2;
  char* scr = ws + off;   // scratch arena (manually aliased, peak ~113 MiB)

  unsigned short* h_bf   = (unsigned short*)(scr + 0);
  unsigned short* qdown  = (unsigned short*)(scr + 16777216);
  float*          kvlr   = (float*)(scr + 29360128);
  unsigned short* qlat   = (unsigned short*)(scr + 0);           // reuses h (dead)
  unsigned short* qgemm  = (unsigned short*)(scr + 38797312);
  unsigned short* kvnorm = (unsigned short*)(scr + 63963136);
  unsigned short* kv     = (unsigned short*)(scr + 68157440);
  unsigned short* qattn  = (unsigned short*)(scr + 0);           // reuses h/qdown/qlat
  unsigned short* kattn  = (unsigned short*)(scr + 38797312);    // reuses qgemm
  unsigned short* attn   = (unsigned short*)(scr + 101711872);
  unsigned short* h2     = (unsigned short*)(scr + 0);
  unsigned short* mbuf   = (unsigned short*)(scr + 16777216);

  auto T = [&](const float* W, unsigned short* Wt, int K, int N) {
    wt_kernel<<<dim3(N / 32, K / 32), 256, 0, stream>>>(W, Wt, K, N);
  };
  T(Wqd, Wqd_t, DM, QL);
  T(Wqu, Wqu_t, QL, H_ * DQK);
  T(Wkvd, Wkvd_t, DM, KVL + ROPE_);
  T(Wkvu, Wkvu_t, KVL, 4096);
  T(Wo, Wo_t, DM, DM);
  T(Wg, Wg_t, DM, DFF);
  T(Wu, Wu_t, DM, DFF);
  T(Wd, Wd_t, DFF, DM);

  // 1. h = rmsnorm(hidden, ln1)
  rms_kernel<float><<<NT, 256, 0, stream>>>(hidden, h_bf, ln1, DM, DM);
  // 2. qdown = h @ Wq_down  (bf16)
  gemm_kernel<0><<<dim3(QL / 64, NT / 64), 256, 0, stream>>>(h_bf, Wqd_t, qdown, nullptr, NT, QL, DM);
  // 3. kvlr = h @ Wkv_down  (f32)
  gemm_kernel<1><<<dim3((KVL + ROPE_) / 64, NT / 64), 256, 0, stream>>>(h_bf, Wkvd_t, kvlr, nullptr, NT, KVL + ROPE_, DM);
  // 4. qlat = rmsnorm(qdown)
  rms_kernel<unsigned short><<<NT, 256, 0, stream>>>(qdown, qlat, nullptr, QL, QL);
  // 5. qgemm = qlat @ Wq_up (bf16)
  gemm_kernel<0><<<dim3(H_ * DQK / 64, NT / 64), 256, 0, stream>>>(qlat, Wqu_t, qgemm, nullptr, NT, H_ * DQK, QL);
  // 6. kvnorm = rmsnorm(kvlr[:, :512])
  rms_kernel<float><<<NT, 256, 0, stream>>>(kvlr, kvnorm, nullptr, KVL, KVL + ROPE_);
  // 7. kv = kvnorm @ Wkv_up (bf16)
  gemm_kernel<0><<<dim3(4096 / 64, NT / 64), 256, 0, stream>>>(kvnorm, Wkvu_t, kv, nullptr, NT, 4096, KVL);
  // 8/9. assemble Q and K with RoPE
  int nbq = (NT * H_ * 96 + 255) / 256;
  build_q_kernel<<<nbq, 256, 0, stream>>>(qgemm, fcos, fsin, qattn);
  build_k_kernel<<<nbq, 256, 0, stream>>>(kvlr, kv, fcos, fsin, kattn);
  // 10. attention
  attn_kernel<<<dim3(S_ / 64, B_ * H_), 256, 0, stream>>>(qattn, kattn, kv, seqmask, attn);
  // 11. x = hidden + attn @ Wo   -> d_out (f32)
  gemm_kernel<2><<<dim3(DM / 64, NT / 64), 256, 0, stream>>>(attn, Wo_t, out, hidden, NT, DM, DM);
  // 12. h2 = rmsnorm(x, ln2)
  rms_kernel<float><<<NT, 256, 0, stream>>>(out, h2, ln2, DM, DM);
  // 13. mbuf = silu(h2@Wg) * (h2@Wu)
  gemm_gateup_kernel<<<dim3(DFF / 64, NT / 64), 256, 0, stream>>>(h2, Wg_t, Wu_t, mbuf, NT, DFF, DM);
  // 14. out = x + mbuf @ Wdown
  gemm_kernel<2><<<dim3(DM / 64, NT / 64), 256, 0, stream>>>(mbuf, Wd_t, out, out, NT, DM, DFF);

  (void)in_sizes; (void)n_in; (void)out_size; (void)ws_size;
}

// Round 2
// 2054.510 us; speedup vs baseline: 2.6058x; 2.6058x over previous
//
#include <hip/hip_runtime.h>
#include <hip/hip_bf16.h>
#include <stdint.h>

// ---------------- problem constants ----------------
#define B_    2
#define S_    2048
#define H_    16
#define DM    2048
#define QL    1536
#define KVL   512
#define NOPE_ 128
#define ROPE_ 64
#define DQK   192
#define DV    128
#define DFF   8192
#define NT    (B_ * S_)          // 4096 token rows
#define EPS_  1e-5f

typedef __bf16 bf16x8 __attribute__((ext_vector_type(8)));
typedef float  f32x4  __attribute__((ext_vector_type(4)));

__device__ __forceinline__ unsigned short f2bf(float f) {
  union { float f; uint32_t u; } v; v.f = f;
  uint32_t r = v.u + 0x7fffu + ((v.u >> 16) & 1u);
  return (unsigned short)(r >> 16);
}
__device__ __forceinline__ float bf2f(unsigned short h) {
  union { uint32_t u; float f; } v; v.u = ((uint32_t)h) << 16;
  return v.f;
}
__device__ __forceinline__ float ldv(float x) { return x; }
__device__ __forceinline__ float ldv(unsigned short x) { return bf2f(x); }

// async global->LDS, 16B per lane; LDS dest = wave-uniform base + lane*16
__device__ __forceinline__ void g2l16(const unsigned short* g, unsigned short* l) {
  __builtin_amdgcn_global_load_lds((const __attribute__((address_space(1))) unsigned int*)g,
                                   (__attribute__((address_space(3))) unsigned int*)l,
                                   16, 0, 0);
}

// ---------------- weight transpose + bf16 convert: W(K,N) f32 -> Wt(N,K) bf16 ----------------
__global__ __launch_bounds__(256) void wt_kernel(const float* __restrict__ W,
                                                 unsigned short* __restrict__ Wt,
                                                 int K, int N) {
  __shared__ unsigned short tile[32][33];
  int kt = blockIdx.y * 32, nt = blockIdx.x * 32;
  int tx = threadIdx.x & 31, ty = threadIdx.x >> 5;   // ty 0..7
#pragma unroll
  for (int kk = 0; kk < 32; kk += 8)
    tile[kk + ty][tx] = f2bf(W[(size_t)(kt + kk + ty) * N + nt + tx]);   // coalesced in n
  __syncthreads();
#pragma unroll
  for (int nn = 0; nn < 32; nn += 8)
    Wt[(size_t)(nt + nn + ty) * K + kt + tx] = tile[tx][nn + ty];        // coalesced in k
}

// ---------------- RMSNorm: rows x D (row stride ldin), optional weight, out bf16 ----------------
template <typename TIN>
__global__ __launch_bounds__(256) void rms_kernel(const TIN* __restrict__ in,
                                                  unsigned short* __restrict__ out,
                                                  const float* __restrict__ w,
                                                  int D, int ldin) {
  int row = blockIdx.x, tid = threadIdx.x;
  const TIN* rp = in + (size_t)row * ldin;
  float ss = 0.f;
  for (int i = tid; i < D; i += 256) { float v = ldv(rp[i]); ss += v * v; }
#pragma unroll
  for (int off = 32; off >= 1; off >>= 1) ss += __shfl_xor(ss, off);
  __shared__ float red[4];
  if ((tid & 63) == 0) red[tid >> 6] = ss;
  __syncthreads();
  ss = red[0] + red[1] + red[2] + red[3];
  float rs = rsqrtf(ss / (float)D + EPS_);
  unsigned short* op = out + (size_t)row * D;
  for (int i = tid; i < D; i += 256) {
    float v = ldv(rp[i]) * rs;
    if (w) v *= w[i];
    op[i] = f2bf(v);
  }
}

// ---------------- tiled bf16 MFMA GEMM (m97 structure): C(M,N) = A(M,K) @ Bt(N,K)^T ----------------
// block 256 = 4 waves (2x2), block tile 128x128, wave tile 64x64 (4x4 MFMA 16x16x32), BK=32
// LDS: As/Bs 128x32 bf16, staged via global_load_lds width-16 (unpadded, lane-ordered)
// MODE 0: store bf16   MODE 1: store f32   MODE 2: store f32 = addsrc + acc
template <int MODE>
__global__ __launch_bounds__(256) void gemm128(const unsigned short* __restrict__ A,
                                               const unsigned short* __restrict__ Bt,
                                               void* C, const float* __restrict__ addsrc,
                                               int M, int N, int K) {
  __shared__ unsigned short As[128 * 32];
  __shared__ unsigned short Bs[128 * 32];
  int tid = threadIdx.x, lane = tid & 63, wave = tid >> 6;
  int quad = lane >> 4, l16 = lane & 15;
  int wm = wave >> 1, wn = wave & 1;
  int m0 = blockIdx.y * 128, n0 = blockIdx.x * 128;

  // staging: round r in {0,1}: flat elem f = r*2048 + tid*8; row = f/32, col = f%32
  int f0 = tid * 8;
  int rs0 = f0 >> 5, cs0 = f0 & 31;
  const unsigned short* Ag0 = A + (size_t)(m0 + rs0) * K + cs0;
  const unsigned short* Ag1 = A + (size_t)(m0 + 64 + rs0) * K + cs0;
  const unsigned short* Bg0 = Bt + (size_t)(n0 + rs0) * K + cs0;
  const unsigned short* Bg1 = Bt + (size_t)(n0 + 64 + rs0) * K + cs0;

  const unsigned short* ArdBase = As + quad * 8 + (wm * 64 + l16) * 32;
  const unsigned short* BrdBase = Bs + quad * 8 + (wn * 64 + l16) * 32;

  f32x4 ac[4][4] = {};
  for (int k = 0; k < K; k += 32) {
    __syncthreads();
    g2l16(Ag0 + k, (unsigned short*)As + f0);
    g2l16(Ag1 + k, (unsigned short*)As + 2048 + f0);
    g2l16(Bg0 + k, (unsigned short*)Bs + f0);
    g2l16(Bg1 + k, (unsigned short*)Bs + 2048 + f0);
    __syncthreads();
    bf16x8 af[4], bfr[4];
#pragma unroll
    for (int mt = 0; mt < 4; ++mt) af[mt]  = *(const bf16x8*)(ArdBase + mt * 16 * 32);
#pragma unroll
    for (int nt = 0; nt < 4; ++nt) bfr[nt] = *(const bf16x8*)(BrdBase + nt * 16 * 32);
#pragma unroll
    for (int mt = 0; mt < 4; ++mt)
#pragma unroll
      for (int nt = 0; nt < 4; ++nt)
        ac[mt][nt] = __builtin_amdgcn_mfma_f32_16x16x32_bf16(af[mt], bfr[nt], ac[mt][nt], 0, 0, 0);
  }

#pragma unroll
  for (int mt = 0; mt < 4; ++mt)
#pragma unroll
    for (int nt = 0; nt < 4; ++nt)
#pragma unroll
      for (int r = 0; r < 4; ++r) {
        int row = m0 + wm * 64 + mt * 16 + quad * 4 + r;
        int col = n0 + wn * 64 + nt * 16 + l16;
        size_t idx = (size_t)row * N + col;
        float v = ac[mt][nt][r];
        if (MODE == 0)      ((unsigned short*)C)[idx] = f2bf(v);
        else if (MODE == 1) ((float*)C)[idx] = v;
        else                ((float*)C)[idx] = addsrc[idx] + v;
      }
}

// ---------------- legacy 64x64 GEMM (register-only) for N not multiple of 128 ----------------
template <int MODE>
__global__ __launch_bounds__(256) void gemm_kernel(const unsigned short* __restrict__ A,
                                                   const unsigned short* __restrict__ Bt,
                                                   void* C, const float* addsrc,
                                                   int M, int N, int K) {
  int lane = threadIdx.x & 63, wave = threadIdx.x >> 6;
  int quad = lane >> 4, l16 = lane & 15;
  int row0 = blockIdx.y * 64 + wave * 16;
  int col0 = blockIdx.x * 64;
  const unsigned short* Ap = A + (size_t)(row0 + l16) * K + quad * 8;
  const unsigned short* Bp = Bt + (size_t)(col0 + l16) * K + quad * 8;
  size_t bs16 = (size_t)16 * K;
  f32x4 ac[4] = {};
  for (int k = 0; k < K; k += 32) {
    bf16x8 a = *(const bf16x8*)(Ap + k);
#pragma unroll
    for (int t = 0; t < 4; ++t) {
      bf16x8 b = *(const bf16x8*)(Bp + bs16 * t + k);
      ac[t] = __builtin_amdgcn_mfma_f32_16x16x32_bf16(a, b, ac[t], 0, 0, 0);
    }
  }
#pragma unroll
  for (int t = 0; t < 4; ++t)
#pragma unroll
    for (int r = 0; r < 4; ++r) {
      int row = row0 + quad * 4 + r, col = col0 + t * 16 + l16;
      size_t idx = (size_t)row * N + col;
      float v = ac[t][r];
      if (MODE == 0)      ((unsigned short*)C)[idx] = f2bf(v);
      else if (MODE == 1) ((float*)C)[idx] = v;
      else                ((float*)C)[idx] = addsrc[idx] + v;
    }
}

// ---------------- elementwise silu(g)*u, vectorized by 8, in-place capable ----------------
__global__ __launch_bounds__(256) void silumul_kernel(const unsigned short* __restrict__ g,
                                                      const unsigned short* __restrict__ u,
                                                      unsigned short* __restrict__ o, int n8) {
  int i = blockIdx.x * 256 + threadIdx.x;
  if (i >= n8) return;
  uint4 gv = ((const uint4*)g)[i];
  uint4 uv = ((const uint4*)u)[i];
  const unsigned short* gp = (const unsigned short*)&gv;
  const unsigned short* up = (const unsigned short*)&uv;
  uint4 ov;
  unsigned short* op = (unsigned short*)&ov;
#pragma unroll
  for (int j = 0; j < 8; ++j) {
    float gf = bf2f(gp[j]), uf = bf2f(up[j]);
    float s = gf / (1.f + __expf(-gf));
    op[j] = f2bf(s * uf);
  }
  ((uint4*)o)[i] = ov;
}

// ---------------- build Q with RoPE: qg(NT, H*192 bf16) -> qo(NT,H,192) = [rope(64)|nope(128)] ----------------
__global__ __launch_bounds__(256) void build_q_kernel(const unsigned short* __restrict__ qg,
                                                      const float* __restrict__ fcos,
                                                      const float* __restrict__ fsin,
                                                      unsigned short* __restrict__ qo) {
  int idx = blockIdx.x * 256 + threadIdx.x;
  if (idx >= NT * H_ * 96) return;
  int i = idx % 96, t = idx / 96;
  int h = t % H_, bs = t / H_, s = bs % S_;
  const unsigned short* src = qg + (size_t)bs * (H_ * DQK) + h * DQK;
  unsigned short* dst = qo + ((size_t)bs * H_ + h) * DQK;
  if (i < 32) {
    float xr = bf2f(src[NOPE_ + 2 * i]), xi = bf2f(src[NOPE_ + 2 * i + 1]);
    float c = fcos[s * 32 + i], sn = fsin[s * 32 + i];
    dst[2 * i]     = f2bf(xr * c - xi * sn);
    dst[2 * i + 1] = f2bf(xr * sn + xi * c);
  } else {
    int j = i - 32;
    dst[ROPE_ + 2 * j]     = src[2 * j];
    dst[ROPE_ + 2 * j + 1] = src[2 * j + 1];
  }
}

// ---------------- build K: rope(kv_lr[:,512:576]) broadcast + k_nope from kv ----------------
__global__ __launch_bounds__(256) void build_k_kernel(const float* __restrict__ kvlr,
                                                      const unsigned short* __restrict__ kv,
                                                      const float* __restrict__ fcos,
                                                      const float* __restrict__ fsin,
                                                      unsigned short* __restrict__ ko) {
  int idx = blockIdx.x * 256 + threadIdx.x;
  if (idx >= NT * H_ * 96) return;
  int i = idx % 96, t = idx / 96;
  int h = t % H_, bs = t / H_, s = bs % S_;
  unsigned short* dst = ko + ((size_t)bs * H_ + h) * DQK;
  if (i < 32) {
    float xr = kvlr[(size_t)bs * (KVL + ROPE_) + KVL + 2 * i];
    float xi = kvlr[(size_t)bs * (KVL + ROPE_) + KVL + 2 * i + 1];
    float c = fcos[s * 32 + i], sn = fsin[s * 32 + i];
    dst[2 * i]     = f2bf(xr * c - xi * sn);
    dst[2 * i + 1] = f2bf(xr * sn + xi * c);
  } else {
    int j = i - 32;
    dst[ROPE_ + 2 * j]     = kv[(size_t)bs * 4096 + h * DV + 2 * j];
    dst[ROPE_ + 2 * j + 1] = kv[(size_t)bs * 4096 + h * DV + 2 * j + 1];
  }
}

// ---------------- flash attention: Br=64 (4 waves x 16 rows), Bc=32, MFMA QK^T and PV ----------------
__global__ __launch_bounds__(256) void attn_kernel(const unsigned short* __restrict__ Q,
                                                   const unsigned short* __restrict__ Kt,
                                                   const unsigned short* __restrict__ KV,
                                                   const int* __restrict__ smaskg,
                                                   unsigned short* __restrict__ O) {
  __shared__ unsigned short Qs[64 * DQK];
  __shared__ unsigned short Ks[32 * DQK];
  __shared__ unsigned short Vts[DV * 32];
  __shared__ unsigned short Ps[4][16 * 32];
  __shared__ int smask[32];

  const float SCALE = 0.07216878364870323f; // 1/sqrt(192)
  int tid = threadIdx.x, wave = tid >> 6, lane = tid & 63;
  int quad = lane >> 4, l16 = lane & 15;
  int bh = blockIdx.y, b = bh / H_, h = bh % H_;
  int r0 = blockIdx.x * 64;

  size_t qbase = ((size_t)(b * S_ + r0) * H_ + h) * DQK;
  for (int i = tid; i < 64 * DQK / 8; i += 256) {
    int row = i / 24, dd = (i % 24) * 8;
    *(uint4*)(Qs + row * DQK + dd) = *(const uint4*)(Q + qbase + (size_t)row * H_ * DQK + dd);
  }

  float m_[4] = {-3e38f, -3e38f, -3e38f, -3e38f};
  float l_[4] = {0.f, 0.f, 0.f, 0.f};
  f32x4 o_[8] = {};

  int ktend = (r0 + 64) / 32;
  for (int kt = 0; kt < ktend; ++kt) {
    int j0 = kt * 32;
    __syncthreads();
    size_t kbase = ((size_t)(b * S_ + j0) * H_ + h) * DQK;
    for (int i = tid; i < 32 * DQK / 8; i += 256) {
      int row = i / 24, dd = (i % 24) * 8;
      *(uint4*)(Ks + row * DQK + dd) = *(const uint4*)(Kt + kbase + (size_t)row * H_ * DQK + dd);
    }
    size_t vbase = (size_t)(b * S_ + j0) * 4096 + H_ * NOPE_ + h * DV;
    for (int i = tid; i < 32 * DV; i += 256) {
      int key = i >> 7, dd = i & 127;
      Vts[dd * 32 + key] = KV[vbase + (size_t)key * 4096 + dd];
    }
    if (tid < 32) smask[tid] = smaskg[b * S_ + j0 + tid];
    __syncthreads();

    f32x4 sc0 = {0.f, 0.f, 0.f, 0.f}, sc1 = {0.f, 0.f, 0.f, 0.f};
    const unsigned short* qrow  = Qs + (wave * 16 + l16) * DQK + quad * 8;
    const unsigned short* krow0 = Ks + l16 * DQK + quad * 8;
    const unsigned short* krow1 = Ks + (16 + l16) * DQK + quad * 8;
#pragma unroll
    for (int kk = 0; kk < DQK; kk += 32) {
      bf16x8 a = *(const bf16x8*)(qrow + kk);
      sc0 = __builtin_amdgcn_mfma_f32_16x16x32_bf16(a, *(const bf16x8*)(krow0 + kk), sc0, 0, 0, 0);
      sc1 = __builtin_amdgcn_mfma_f32_16x16x32_bf16(a, *(const bf16x8*)(krow1 + kk), sc1, 0, 0, 0);
    }

    int rowg_base = r0 + wave * 16 + quad * 4;
    bool ok0 = smask[l16] != 0, ok1 = smask[16 + l16] != 0;
    float s0[4], s1[4];
#pragma unroll
    for (int r = 0; r < 4; ++r) {
      int rg = rowg_base + r;
      s0[r] = (ok0 && (j0 + l16) <= rg)      ? sc0[r] * SCALE : -1e30f;
      s1[r] = (ok1 && (j0 + 16 + l16) <= rg) ? sc1[r] * SCALE : -1e30f;
    }
#pragma unroll
    for (int r = 0; r < 4; ++r) {
      float tm = fmaxf(s0[r], s1[r]);
      tm = fmaxf(tm, __shfl_xor(tm, 1));
      tm = fmaxf(tm, __shfl_xor(tm, 2));
      tm = fmaxf(tm, __shfl_xor(tm, 4));
      tm = fmaxf(tm, __shfl_xor(tm, 8));
      float mn = fmaxf(m_[r], tm);
      float al = __expf(m_[r] - mn);
      m_[r] = mn;
      float p0 = __expf(s0[r] - mn);
      float p1 = __expf(s1[r] - mn);
      float ps = p0 + p1;
      ps += __shfl_xor(ps, 1);
      ps += __shfl_xor(ps, 2);
      ps += __shfl_xor(ps, 4);
      ps += __shfl_xor(ps, 8);
      l_[r] = l_[r] * al + ps;
#pragma unroll
      for (int nt = 0; nt < 8; ++nt) o_[nt][r] *= al;
      Ps[wave][(quad * 4 + r) * 32 + l16]      = f2bf(p0);
      Ps[wave][(quad * 4 + r) * 32 + 16 + l16] = f2bf(p1);
    }

    bf16x8 pa = *(const bf16x8*)(&Ps[wave][l16 * 32 + quad * 8]);
#pragma unroll
    for (int nt = 0; nt < 8; ++nt) {
      bf16x8 vb = *(const bf16x8*)(&Vts[(nt * 16 + l16) * 32 + quad * 8]);
      o_[nt] = __builtin_amdgcn_mfma_f32_16x16x32_bf16(pa, vb, o_[nt], 0, 0, 0);
    }
  }

#pragma unroll
  for (int nt = 0; nt < 8; ++nt)
#pragma unroll
    for (int r = 0; r < 4; ++r) {
      int rg = r0 + wave * 16 + quad * 4 + r;
      float v = o_[nt][r] / l_[r];
      O[((size_t)(b * S_ + rg) * H_ + h) * DV + nt * 16 + l16] = f2bf(v);
    }
}

// ---------------- host launch ----------------
extern "C" void kernel_launch(void* const* d_in, const int* in_sizes, int n_in,
                              void* d_out, int out_size, void* d_ws, size_t ws_size,
                              hipStream_t stream) {
  const float* hidden  = (const float*)d_in[0];
  const int*   seqmask = (const int*)d_in[1];
  const float* fcos    = (const float*)d_in[2];
  const float* fsin    = (const float*)d_in[3];
  const float* ln1     = (const float*)d_in[4];
  const float* ln2     = (const float*)d_in[5];
  const float* Wqd     = (const float*)d_in[6];
  const float* Wqu     = (const float*)d_in[7];
  const float* Wkvd    = (const float*)d_in[8];
  const float* Wkvu    = (const float*)d_in[9];
  const float* Wo      = (const float*)d_in[10];
  const float* Wg      = (const float*)d_in[11];
  const float* Wu      = (const float*)d_in[12];
  const float* Wd      = (const float*)d_in[13];
  float* out = (float*)d_out;
  char* ws = (char*)d_ws;

  // weight arena (bf16, transposed N x K)
  size_t off = 0;
  unsigned short* Wqd_t  = (unsigned short*)(ws + off); off += (size_t)QL * DM * 2;
  unsigned short* Wqu_t  = (unsigned short*)(ws + off); off += (size_t)(H_ * DQK) * QL * 2;
  unsigned short* Wkvd_t = (unsigned short*)(ws + off); off += (size_t)(KVL + ROPE_) * DM * 2;
  unsigned short* Wkvu_t = (unsigned short*)(ws + off); off += (size_t)4096 * KVL * 2;
  unsigned short* Wo_t   = (unsigned short*)(ws + off); off += (size_t)DM * DM * 2;
  unsigned short* Wg_t   = (unsigned short*)(ws + off); off += (size_t)DFF * DM * 2;
  unsigned short* Wu_t   = (unsigned short*)(ws + off); off += (size_t)DFF * DM * 2;
  unsigned short* Wd_t   = (unsigned short*)(ws + off); off += (size_t)DM * DFF * 2;
  char* scr = ws + off;

  unsigned short* h_bf   = (unsigned short*)(scr + 0);
  unsigned short* qdown  = (unsigned short*)(scr + 16777216);
  float*          kvlr   = (float*)(scr + 29360128);
  unsigned short* qlat   = (unsigned short*)(scr + 0);           // after kvdown GEMM, h dead
  unsigned short* qgemm  = (unsigned short*)(scr + 38797312);
  unsigned short* kvnorm = (unsigned short*)(scr + 63963136);
  unsigned short* kv     = (unsigned short*)(scr + 68157440);
  unsigned short* qattn  = (unsigned short*)(scr + 0);
  unsigned short* kattn  = (unsigned short*)(scr + 38797312);
  unsigned short* attn   = (unsigned short*)(scr + 101711872);
  unsigned short* h2     = (unsigned short*)(scr + 0);
  unsigned short* gbuf   = (unsigned short*)(scr + 16777216);    // 64 MB
  unsigned short* ubuf   = (unsigned short*)(scr + 83886080);    // 64 MB

  auto T = [&](const float* W, unsigned short* Wt, int K, int N) {
    wt_kernel<<<dim3(N / 32, K / 32), 256, 0, stream>>>(W, Wt, K, N);
  };
  T(Wqd, Wqd_t, DM, QL);
  T(Wqu, Wqu_t, QL, H_ * DQK);
  T(Wkvd, Wkvd_t, DM, KVL + ROPE_);
  T(Wkvu, Wkvu_t, KVL, 4096);
  T(Wo, Wo_t, DM, DM);
  T(Wg, Wg_t, DM, DFF);
  T(Wu, Wu_t, DM, DFF);
  T(Wd, Wd_t, DFF, DM);

  // 1. h = rmsnorm(hidden, ln1)
  rms_kernel<float><<<NT, 256, 0, stream>>>(hidden, h_bf, ln1, DM, DM);
  // 2. qdown = h @ Wq_down  (bf16)
  gemm128<0><<<dim3(QL / 128, NT / 128), 256, 0, stream>>>(h_bf, Wqd_t, qdown, nullptr, NT, QL, DM);
  // 3. kvlr = h @ Wkv_down  (f32, N=576 -> legacy 64-tile)
  gemm_kernel<1><<<dim3((KVL + ROPE_) / 64, NT / 64), 256, 0, stream>>>(h_bf, Wkvd_t, kvlr, nullptr, NT, KVL + ROPE_, DM);
  // 4. qlat = rmsnorm(qdown)
  rms_kernel<unsigned short><<<NT, 256, 0, stream>>>(qdown, qlat, nullptr, QL, QL);
  // 5. qgemm = qlat @ Wq_up (bf16)
  gemm128<0><<<dim3(H_ * DQK / 128, NT / 128), 256, 0, stream>>>(qlat, Wqu_t, qgemm, nullptr, NT, H_ * DQK, QL);
  // 6. kvnorm = rmsnorm(kvlr[:, :512])
  rms_kernel<float><<<NT, 256, 0, stream>>>(kvlr, kvnorm, nullptr, KVL, KVL + ROPE_);
  // 7. kv = kvnorm @ Wkv_up (bf16)
  gemm128<0><<<dim3(4096 / 128, NT / 128), 256, 0, stream>>>(kvnorm, Wkvu_t, kv, nullptr, NT, 4096, KVL);
  // 8/9. assemble Q and K with RoPE
  int nbq = (NT * H_ * 96 + 255) / 256;
  build_q_kernel<<<nbq, 256, 0, stream>>>(qgemm, fcos, fsin, qattn);
  build_k_kernel<<<nbq, 256, 0, stream>>>(kvlr, kv, fcos, fsin, kattn);
  // 10. attention
  attn_kernel<<<dim3(S_ / 64, B_ * H_), 256, 0, stream>>>(qattn, kattn, kv, seqmask, attn);
  // 11. x = hidden + attn @ Wo   -> d_out (f32)
  gemm128<2><<<dim3(DM / 128, NT / 128), 256, 0, stream>>>(attn, Wo_t, out, hidden, NT, DM, DM);
  // 12. h2 = rmsnorm(x, ln2)
  rms_kernel<float><<<NT, 256, 0, stream>>>(out, h2, ln2, DM, DM);
  // 13. gbuf = h2@Wg ; ubuf = h2@Wu ; gbuf = silu(gbuf)*ubuf
  gemm128<0><<<dim3(DFF / 128, NT / 128), 256, 0, stream>>>(h2, Wg_t, gbuf, nullptr, NT, DFF, DM);
  gemm128<0><<<dim3(DFF / 128, NT / 128), 256, 0, stream>>>(h2, Wu_t, ubuf, nullptr, NT, DFF, DM);
  silumul_kernel<<<(NT * DFF / 8 + 255) / 256, 256, 0, stream>>>(gbuf, ubuf, gbuf, NT * DFF / 8);
  // 14. out = x + gbuf @ Wdown
  gemm128<2><<<dim3(DM / 128, NT / 128), 256, 0, stream>>>(gbuf, Wd_t, out, out, NT, DM, DFF);

  (void)in_sizes; (void)n_in; (void)out_size; (void)ws_size;
}

// Round 3
// 1565.719 us; speedup vs baseline: 3.4192x; 1.3122x over previous
//
#include <hip/hip_runtime.h>
#include <hip/hip_bf16.h>
#include <stdint.h>

// ---------------- problem constants ----------------
#define B_    2
#define S_    2048
#define H_    16
#define DM    2048
#define QL    1536
#define KVL   512
#define NOPE_ 128
#define ROPE_ 64
#define DQK   192
#define DV    128
#define DFF   8192
#define NT    (B_ * S_)          // 4096 token rows
#define EPS_  1e-5f

typedef __bf16 bf16x8 __attribute__((ext_vector_type(8)));
typedef float  f32x4  __attribute__((ext_vector_type(4)));

__device__ __forceinline__ unsigned short f2bf(float f) {
  union { float f; uint32_t u; } v; v.f = f;
  uint32_t r = v.u + 0x7fffu + ((v.u >> 16) & 1u);
  return (unsigned short)(r >> 16);
}
__device__ __forceinline__ float bf2f(unsigned short h) {
  union { uint32_t u; float f; } v; v.u = ((uint32_t)h) << 16;
  return v.f;
}
__device__ __forceinline__ float ldv(float x) { return x; }
__device__ __forceinline__ float ldv(unsigned short x) { return bf2f(x); }

// async global->LDS, 16B per lane; LDS dest = wave-uniform base + lane*16
__device__ __forceinline__ void g2l16(const unsigned short* g, unsigned short* l) {
  __builtin_amdgcn_global_load_lds((const __attribute__((address_space(1))) unsigned int*)g,
                                   (__attribute__((address_space(3))) unsigned int*)l,
                                   16, 0, 0);
}

// ---------------- weight transpose + bf16 convert: W(K,N) f32 -> Wt(N,K) bf16 ----------------
__global__ __launch_bounds__(256) void wt_kernel(const float* __restrict__ W,
                                                 unsigned short* __restrict__ Wt,
                                                 int K, int N) {
  __shared__ unsigned short tile[32][33];
  int kt = blockIdx.y * 32, nt = blockIdx.x * 32;
  int tx = threadIdx.x & 31, ty = threadIdx.x >> 5;   // ty 0..7
#pragma unroll
  for (int kk = 0; kk < 32; kk += 8)
    tile[kk + ty][tx] = f2bf(W[(size_t)(kt + kk + ty) * N + nt + tx]);   // coalesced in n
  __syncthreads();
#pragma unroll
  for (int nn = 0; nn < 32; nn += 8)
    Wt[(size_t)(nt + nn + ty) * K + kt + tx] = tile[tx][nn + ty];        // coalesced in k
}

// ---------------- RMSNorm: rows x D (row stride ldin), optional weight, out bf16 ----------------
template <typename TIN>
__global__ __launch_bounds__(256) void rms_kernel(const TIN* __restrict__ in,
                                                  unsigned short* __restrict__ out,
                                                  const float* __restrict__ w,
                                                  int D, int ldin) {
  int row = blockIdx.x, tid = threadIdx.x;
  const TIN* rp = in + (size_t)row * ldin;
  float ss = 0.f;
  for (int i = tid; i < D; i += 256) { float v = ldv(rp[i]); ss += v * v; }
#pragma unroll
  for (int off = 32; off >= 1; off >>= 1) ss += __shfl_xor(ss, off);
  __shared__ float red[4];
  if ((tid & 63) == 0) red[tid >> 6] = ss;
  __syncthreads();
  ss = red[0] + red[1] + red[2] + red[3];
  float rs = rsqrtf(ss / (float)D + EPS_);
  unsigned short* op = out + (size_t)row * D;
  for (int i = tid; i < D; i += 256) {
    float v = ldv(rp[i]) * rs;
    if (w) v *= w[i];
    op[i] = f2bf(v);
  }
}

// ---------------- tiled bf16 MFMA GEMM (m97 structure): C(M,N) = A(M,K) @ Bt(N,K)^T ----------------
template <int MODE>
__global__ __launch_bounds__(256) void gemm128(const unsigned short* __restrict__ A,
                                               const unsigned short* __restrict__ Bt,
                                               void* C, const float* __restrict__ addsrc,
                                               int M, int N, int K) {
  __shared__ unsigned short As[128 * 32];
  __shared__ unsigned short Bs[128 * 32];
  int tid = threadIdx.x, lane = tid & 63, wave = tid >> 6;
  int quad = lane >> 4, l16 = lane & 15;
  int wm = wave >> 1, wn = wave & 1;
  int m0 = blockIdx.y * 128, n0 = blockIdx.x * 128;

  int f0 = tid * 8;
  int rs0 = f0 >> 5, cs0 = f0 & 31;
  const unsigned short* Ag0 = A + (size_t)(m0 + rs0) * K + cs0;
  const unsigned short* Ag1 = A + (size_t)(m0 + 64 + rs0) * K + cs0;
  const unsigned short* Bg0 = Bt + (size_t)(n0 + rs0) * K + cs0;
  const unsigned short* Bg1 = Bt + (size_t)(n0 + 64 + rs0) * K + cs0;

  const unsigned short* ArdBase = As + quad * 8 + (wm * 64 + l16) * 32;
  const unsigned short* BrdBase = Bs + quad * 8 + (wn * 64 + l16) * 32;

  f32x4 ac[4][4] = {};
  for (int k = 0; k < K; k += 32) {
    __syncthreads();
    g2l16(Ag0 + k, (unsigned short*)As + f0);
    g2l16(Ag1 + k, (unsigned short*)As + 2048 + f0);
    g2l16(Bg0 + k, (unsigned short*)Bs + f0);
    g2l16(Bg1 + k, (unsigned short*)Bs + 2048 + f0);
    __syncthreads();
    bf16x8 af[4], bfr[4];
#pragma unroll
    for (int mt = 0; mt < 4; ++mt) af[mt]  = *(const bf16x8*)(ArdBase + mt * 16 * 32);
#pragma unroll
    for (int nt = 0; nt < 4; ++nt) bfr[nt] = *(const bf16x8*)(BrdBase + nt * 16 * 32);
#pragma unroll
    for (int mt = 0; mt < 4; ++mt)
#pragma unroll
      for (int nt = 0; nt < 4; ++nt)
        ac[mt][nt] = __builtin_amdgcn_mfma_f32_16x16x32_bf16(af[mt], bfr[nt], ac[mt][nt], 0, 0, 0);
  }

#pragma unroll
  for (int mt = 0; mt < 4; ++mt)
#pragma unroll
    for (int nt = 0; nt < 4; ++nt)
#pragma unroll
      for (int r = 0; r < 4; ++r) {
        int row = m0 + wm * 64 + mt * 16 + quad * 4 + r;
        int col = n0 + wn * 64 + nt * 16 + l16;
        size_t idx = (size_t)row * N + col;
        float v = ac[mt][nt][r];
        if (MODE == 0)      ((unsigned short*)C)[idx] = f2bf(v);
        else if (MODE == 1) ((float*)C)[idx] = v;
        else                ((float*)C)[idx] = addsrc[idx] + v;
      }
}

// ---------------- legacy 64x64 GEMM (register-only) for N not multiple of 128 ----------------
template <int MODE>
__global__ __launch_bounds__(256) void gemm_kernel(const unsigned short* __restrict__ A,
                                                   const unsigned short* __restrict__ Bt,
                                                   void* C, const float* addsrc,
                                                   int M, int N, int K) {
  int lane = threadIdx.x & 63, wave = threadIdx.x >> 6;
  int quad = lane >> 4, l16 = lane & 15;
  int row0 = blockIdx.y * 64 + wave * 16;
  int col0 = blockIdx.x * 64;
  const unsigned short* Ap = A + (size_t)(row0 + l16) * K + quad * 8;
  const unsigned short* Bp = Bt + (size_t)(col0 + l16) * K + quad * 8;
  size_t bs16 = (size_t)16 * K;
  f32x4 ac[4] = {};
  for (int k = 0; k < K; k += 32) {
    bf16x8 a = *(const bf16x8*)(Ap + k);
#pragma unroll
    for (int t = 0; t < 4; ++t) {
      bf16x8 b = *(const bf16x8*)(Bp + bs16 * t + k);
      ac[t] = __builtin_amdgcn_mfma_f32_16x16x32_bf16(a, b, ac[t], 0, 0, 0);
    }
  }
#pragma unroll
  for (int t = 0; t < 4; ++t)
#pragma unroll
    for (int r = 0; r < 4; ++r) {
      int row = row0 + quad * 4 + r, col = col0 + t * 16 + l16;
      size_t idx = (size_t)row * N + col;
      float v = ac[t][r];
      if (MODE == 0)      ((unsigned short*)C)[idx] = f2bf(v);
      else if (MODE == 1) ((float*)C)[idx] = v;
      else                ((float*)C)[idx] = addsrc[idx] + v;
    }
}

// ---------------- elementwise silu(g)*u, vectorized by 8 ----------------
__global__ __launch_bounds__(256) void silumul_kernel(const unsigned short* __restrict__ g,
                                                      const unsigned short* __restrict__ u,
                                                      unsigned short* __restrict__ o, int n8) {
  int i = blockIdx.x * 256 + threadIdx.x;
  if (i >= n8) return;
  uint4 gv = ((const uint4*)g)[i];
  uint4 uv = ((const uint4*)u)[i];
  const unsigned short* gp = (const unsigned short*)&gv;
  const unsigned short* up = (const unsigned short*)&uv;
  uint4 ov;
  unsigned short* op = (unsigned short*)&ov;
#pragma unroll
  for (int j = 0; j < 8; ++j) {
    float gf = bf2f(gp[j]), uf = bf2f(up[j]);
    float s = gf / (1.f + __expf(-gf));
    op[j] = f2bf(s * uf);
  }
  ((uint4*)o)[i] = ov;
}

// ---------------- build Q with RoPE, PRE-SCALED by 1/sqrt(192) ----------------
__global__ __launch_bounds__(256) void build_q_kernel(const unsigned short* __restrict__ qg,
                                                      const float* __restrict__ fcos,
                                                      const float* __restrict__ fsin,
                                                      unsigned short* __restrict__ qo) {
  const float SCALE = 0.07216878364870323f;
  int idx = blockIdx.x * 256 + threadIdx.x;
  if (idx >= NT * H_ * 96) return;
  int i = idx % 96, t = idx / 96;
  int h = t % H_, bs = t / H_, s = bs % S_;
  const unsigned short* src = qg + (size_t)bs * (H_ * DQK) + h * DQK;
  unsigned short* dst = qo + ((size_t)bs * H_ + h) * DQK;
  if (i < 32) {
    float xr = bf2f(src[NOPE_ + 2 * i]), xi = bf2f(src[NOPE_ + 2 * i + 1]);
    float c = fcos[s * 32 + i], sn = fsin[s * 32 + i];
    dst[2 * i]     = f2bf((xr * c - xi * sn) * SCALE);
    dst[2 * i + 1] = f2bf((xr * sn + xi * c) * SCALE);
  } else {
    int j = i - 32;
    dst[ROPE_ + 2 * j]     = f2bf(bf2f(src[2 * j]) * SCALE);
    dst[ROPE_ + 2 * j + 1] = f2bf(bf2f(src[2 * j + 1]) * SCALE);
  }
}

// ---------------- build K: rope(kv_lr[:,512:576]) broadcast + k_nope from kv ----------------
__global__ __launch_bounds__(256) void build_k_kernel(const float* __restrict__ kvlr,
                                                      const unsigned short* __restrict__ kv,
                                                      const float* __restrict__ fcos,
                                                      const float* __restrict__ fsin,
                                                      unsigned short* __restrict__ ko) {
  int idx = blockIdx.x * 256 + threadIdx.x;
  if (idx >= NT * H_ * 96) return;
  int i = idx % 96, t = idx / 96;
  int h = t % H_, bs = t / H_, s = bs % S_;
  unsigned short* dst = ko + ((size_t)bs * H_ + h) * DQK;
  if (i < 32) {
    float xr = kvlr[(size_t)bs * (KVL + ROPE_) + KVL + 2 * i];
    float xi = kvlr[(size_t)bs * (KVL + ROPE_) + KVL + 2 * i + 1];
    float c = fcos[s * 32 + i], sn = fsin[s * 32 + i];
    dst[2 * i]     = f2bf(xr * c - xi * sn);
    dst[2 * i + 1] = f2bf(xr * sn + xi * c);
  } else {
    int j = i - 32;
    dst[ROPE_ + 2 * j]     = kv[(size_t)bs * 4096 + h * DV + 2 * j];
    dst[ROPE_ + 2 * j + 1] = kv[(size_t)bs * 4096 + h * DV + 2 * j + 1];
  }
}

// ---------------- global V transpose: kv[bs][2048 + h*128 + d] -> vt[bh][d][s] ----------------
__global__ __launch_bounds__(256) void vt_kernel(const unsigned short* __restrict__ kv,
                                                 unsigned short* __restrict__ vt) {
  __shared__ unsigned short t[32][33];
  int bh = blockIdx.z, b = bh >> 4, h = bh & 15;
  int s0 = blockIdx.x * 32, d0 = blockIdx.y * 32;
  int tx = threadIdx.x & 31, ty = threadIdx.x >> 5;
#pragma unroll
  for (int i = 0; i < 32; i += 8)
    t[i + ty][tx] = kv[(size_t)(b * S_ + s0 + i + ty) * 4096 + 2048 + h * 128 + d0 + tx];
  __syncthreads();
#pragma unroll
  for (int i = 0; i < 32; i += 8)
    vt[((size_t)bh * 128 + d0 + i + ty) * S_ + s0 + tx] = t[tx][i + ty];
}

// ---------------- flash attention v2 ----------------
// Br=128 (4 waves x 32 rows), Bc=32. Q fragments in registers (pre-scaled).
// LDS strides padded: K 200, V^T 40, P 40 elems (uniform bank spread, 16B-aligned rows).
#define KSTR 200
#define VSTR 40
#define PSTR 40
__global__ __launch_bounds__(256, 2) void attn2_kernel(const unsigned short* __restrict__ Q,
                                                       const unsigned short* __restrict__ Kt,
                                                       const unsigned short* __restrict__ Vt,
                                                       const int* __restrict__ smaskg,
                                                       unsigned short* __restrict__ O) {
  __shared__ unsigned short Ks[32 * KSTR];   // 12800 B
  __shared__ unsigned short Vts[128 * VSTR]; // 10240 B
  __shared__ unsigned short Ps[4][32 * PSTR];// 10240 B
  __shared__ int smaskl[32];

  int tid = threadIdx.x, wave = tid >> 6, lane = tid & 63;
  int quad = lane >> 4, l16 = lane & 15;
  int bh = blockIdx.y, b = bh >> 4, h = bh & 15;
  int qb = (int)gridDim.x - 1 - (int)blockIdx.x;   // heavy blocks dispatch first
  int r0 = qb * 128;

  // Q fragments in registers (2 m-tiles x 6 k-steps)
  bf16x8 qf[2][6];
#pragma unroll
  for (int mt = 0; mt < 2; ++mt) {
    int rg = r0 + wave * 32 + mt * 16 + l16;
    const unsigned short* qp = Q + ((size_t)(b * S_ + rg) * H_ + h) * DQK + quad * 8;
#pragma unroll
    for (int kk = 0; kk < 6; ++kk)
      qf[mt][kk] = *(const bf16x8*)(qp + kk * 32);
  }

  float m_[2][4], l_[2][4];
  f32x4 o_[2][8] = {};
#pragma unroll
  for (int mt = 0; mt < 2; ++mt)
#pragma unroll
    for (int r = 0; r < 4; ++r) { m_[mt][r] = -3e38f; l_[mt][r] = 0.f; }

  int ktend = 4 * qb + 4;
  for (int kt = 0; kt < ktend; ++kt) {
    int j0 = kt * 32;
    __syncthreads();
    // stage K tile: 32 rows x 192 elems = 768 16B-chunks
#pragma unroll
    for (int i = 0; i < 3; ++i) {
      int c = tid + i * 256;
      int row = c / 24, cc = (c % 24) * 8;
      *(uint4*)(Ks + row * KSTR + cc) =
          *(const uint4*)(Kt + ((size_t)(b * S_ + j0 + row) * H_ + h) * DQK + cc);
    }
    // stage V^T tile: 128 d-rows x 32 keys = 512 chunks
#pragma unroll
    for (int i = 0; i < 2; ++i) {
      int c = tid + i * 256;
      int d = c >> 2, cc = (c & 3) * 8;
      *(uint4*)(Vts + d * VSTR + cc) =
          *(const uint4*)(Vt + ((size_t)bh * 128 + d) * S_ + j0 + cc);
    }
    if (tid < 32) smaskl[tid] = smaskg[b * S_ + j0 + tid];
    __syncthreads();

    // S = Q K^T  (2 m-tiles x 2 n-tiles)
    f32x4 sc[2][2] = {};
#pragma unroll
    for (int kk = 0; kk < 6; ++kk) {
      bf16x8 b0 = *(const bf16x8*)(Ks + l16 * KSTR + kk * 32 + quad * 8);
      bf16x8 b1 = *(const bf16x8*)(Ks + (16 + l16) * KSTR + kk * 32 + quad * 8);
#pragma unroll
      for (int mt = 0; mt < 2; ++mt) {
        sc[mt][0] = __builtin_amdgcn_mfma_f32_16x16x32_bf16(qf[mt][kk], b0, sc[mt][0], 0, 0, 0);
        sc[mt][1] = __builtin_amdgcn_mfma_f32_16x16x32_bf16(qf[mt][kk], b1, sc[mt][1], 0, 0, 0);
      }
    }

    bool ok0 = smaskl[l16] != 0, ok1 = smaskl[16 + l16] != 0;
    int c0 = j0 + l16, c1 = j0 + 16 + l16;
#pragma unroll
    for (int mt = 0; mt < 2; ++mt) {
      int rbase = r0 + wave * 32 + mt * 16 + quad * 4;
#pragma unroll
      for (int r = 0; r < 4; ++r) {
        int rg = rbase + r;
        float s0 = (ok0 && c0 <= rg) ? sc[mt][0][r] : -1e30f;
        float s1 = (ok1 && c1 <= rg) ? sc[mt][1][r] : -1e30f;
        float tm = fmaxf(s0, s1);
        tm = fmaxf(tm, __shfl_xor(tm, 1));
        tm = fmaxf(tm, __shfl_xor(tm, 2));
        tm = fmaxf(tm, __shfl_xor(tm, 4));
        tm = fmaxf(tm, __shfl_xor(tm, 8));
        float mn = fmaxf(m_[mt][r], tm);
        float al = __expf(m_[mt][r] - mn);
        m_[mt][r] = mn;
        float p0 = __expf(s0 - mn);
        float p1 = __expf(s1 - mn);
        float ps = p0 + p1;
        ps += __shfl_xor(ps, 1);
        ps += __shfl_xor(ps, 2);
        ps += __shfl_xor(ps, 4);
        ps += __shfl_xor(ps, 8);
        l_[mt][r] = l_[mt][r] * al + ps;
#pragma unroll
        for (int nt = 0; nt < 8; ++nt) o_[mt][nt][r] *= al;
        int prow = mt * 16 + quad * 4 + r;
        Ps[wave][prow * PSTR + l16]      = f2bf(p0);
        Ps[wave][prow * PSTR + 16 + l16] = f2bf(p1);
      }
    }

    // O += P V  (A = P from per-wave LDS, B = V^T rows)
    bf16x8 pa[2];
#pragma unroll
    for (int mt = 0; mt < 2; ++mt)
      pa[mt] = *(const bf16x8*)(&Ps[wave][(mt * 16 + l16) * PSTR + quad * 8]);
#pragma unroll
    for (int nt = 0; nt < 8; ++nt) {
      bf16x8 vb = *(const bf16x8*)(Vts + (nt * 16 + l16) * VSTR + quad * 8);
#pragma unroll
      for (int mt = 0; mt < 2; ++mt)
        o_[mt][nt] = __builtin_amdgcn_mfma_f32_16x16x32_bf16(pa[mt], vb, o_[mt][nt], 0, 0, 0);
    }
  }

  // epilogue: O layout (B,S,H,DV)
#pragma unroll
  for (int mt = 0; mt < 2; ++mt)
#pragma unroll
    for (int nt = 0; nt < 8; ++nt)
#pragma unroll
      for (int r = 0; r < 4; ++r) {
        int rg = r0 + wave * 32 + mt * 16 + quad * 4 + r;
        float v = o_[mt][nt][r] / l_[mt][r];
        O[((size_t)(b * S_ + rg) * H_ + h) * DV + nt * 16 + l16] = f2bf(v);
      }
}

// ---------------- host launch ----------------
extern "C" void kernel_launch(void* const* d_in, const int* in_sizes, int n_in,
                              void* d_out, int out_size, void* d_ws, size_t ws_size,
                              hipStream_t stream) {
  const float* hidden  = (const float*)d_in[0];
  const int*   seqmask = (const int*)d_in[1];
  const float* fcos    = (const float*)d_in[2];
  const float* fsin    = (const float*)d_in[3];
  const float* ln1     = (const float*)d_in[4];
  const float* ln2     = (const float*)d_in[5];
  const float* Wqd     = (const float*)d_in[6];
  const float* Wqu     = (const float*)d_in[7];
  const float* Wkvd    = (const float*)d_in[8];
  const float* Wkvu    = (const float*)d_in[9];
  const float* Wo      = (const float*)d_in[10];
  const float* Wg      = (const float*)d_in[11];
  const float* Wu      = (const float*)d_in[12];
  const float* Wd      = (const float*)d_in[13];
  float* out = (float*)d_out;
  char* ws = (char*)d_ws;

  // weight arena (bf16, transposed N x K)
  size_t off = 0;
  unsigned short* Wqd_t  = (unsigned short*)(ws + off); off += (size_t)QL * DM * 2;
  unsigned short* Wqu_t  = (unsigned short*)(ws + off); off += (size_t)(H_ * DQK) * QL * 2;
  unsigned short* Wkvd_t = (unsigned short*)(ws + off); off += (size_t)(KVL + ROPE_) * DM * 2;
  unsigned short* Wkvu_t = (unsigned short*)(ws + off); off += (size_t)4096 * KVL * 2;
  unsigned short* Wo_t   = (unsigned short*)(ws + off); off += (size_t)DM * DM * 2;
  unsigned short* Wg_t   = (unsigned short*)(ws + off); off += (size_t)DFF * DM * 2;
  unsigned short* Wu_t   = (unsigned short*)(ws + off); off += (size_t)DFF * DM * 2;
  unsigned short* Wd_t   = (unsigned short*)(ws + off); off += (size_t)DM * DFF * 2;
  char* scr = ws + off;

  unsigned short* h_bf   = (unsigned short*)(scr + 0);
  unsigned short* qdown  = (unsigned short*)(scr + 16777216);
  float*          kvlr   = (float*)(scr + 29360128);
  unsigned short* qlat   = (unsigned short*)(scr + 0);
  unsigned short* qgemm  = (unsigned short*)(scr + 38797312);
  unsigned short* kvnorm = (unsigned short*)(scr + 63963136);
  unsigned short* kv     = (unsigned short*)(scr + 68157440);
  unsigned short* qattn  = (unsigned short*)(scr + 0);
  unsigned short* kattn  = (unsigned short*)(scr + 38797312);
  unsigned short* attn   = (unsigned short*)(scr + 101711872);
  unsigned short* vt     = (unsigned short*)(scr + 118489088);   // 16.8 MB, dead before ubuf use
  unsigned short* h2     = (unsigned short*)(scr + 0);
  unsigned short* gbuf   = (unsigned short*)(scr + 16777216);
  unsigned short* ubuf   = (unsigned short*)(scr + 83886080);

  auto T = [&](const float* W, unsigned short* Wt, int K, int N) {
    wt_kernel<<<dim3(N / 32, K / 32), 256, 0, stream>>>(W, Wt, K, N);
  };
  T(Wqd, Wqd_t, DM, QL);
  T(Wqu, Wqu_t, QL, H_ * DQK);
  T(Wkvd, Wkvd_t, DM, KVL + ROPE_);
  T(Wkvu, Wkvu_t, KVL, 4096);
  T(Wo, Wo_t, DM, DM);
  T(Wg, Wg_t, DM, DFF);
  T(Wu, Wu_t, DM, DFF);
  T(Wd, Wd_t, DFF, DM);

  // 1. h = rmsnorm(hidden, ln1)
  rms_kernel<float><<<NT, 256, 0, stream>>>(hidden, h_bf, ln1, DM, DM);
  // 2. qdown = h @ Wq_down
  gemm128<0><<<dim3(QL / 128, NT / 128), 256, 0, stream>>>(h_bf, Wqd_t, qdown, nullptr, NT, QL, DM);
  // 3. kvlr = h @ Wkv_down (f32, N=576)
  gemm_kernel<1><<<dim3((KVL + ROPE_) / 64, NT / 64), 256, 0, stream>>>(h_bf, Wkvd_t, kvlr, nullptr, NT, KVL + ROPE_, DM);
  // 4. qlat = rmsnorm(qdown)
  rms_kernel<unsigned short><<<NT, 256, 0, stream>>>(qdown, qlat, nullptr, QL, QL);
  // 5. qgemm = qlat @ Wq_up
  gemm128<0><<<dim3(H_ * DQK / 128, NT / 128), 256, 0, stream>>>(qlat, Wqu_t, qgemm, nullptr, NT, H_ * DQK, QL);
  // 6. kvnorm = rmsnorm(kvlr[:, :512])
  rms_kernel<float><<<NT, 256, 0, stream>>>(kvlr, kvnorm, nullptr, KVL, KVL + ROPE_);
  // 7. kv = kvnorm @ Wkv_up
  gemm128<0><<<dim3(4096 / 128, NT / 128), 256, 0, stream>>>(kvnorm, Wkvu_t, kv, nullptr, NT, 4096, KVL);
  // 8/9. assemble Q (pre-scaled) and K with RoPE; transpose V globally
  int nbq = (NT * H_ * 96 + 255) / 256;
  build_q_kernel<<<nbq, 256, 0, stream>>>(qgemm, fcos, fsin, qattn);
  build_k_kernel<<<nbq, 256, 0, stream>>>(kvlr, kv, fcos, fsin, kattn);
  vt_kernel<<<dim3(S_ / 32, DV / 32, B_ * H_), 256, 0, stream>>>(kv, vt);
  // 10. attention
  attn2_kernel<<<dim3(S_ / 128, B_ * H_), 256, 0, stream>>>(qattn, kattn, vt, seqmask, attn);
  // 11. x = hidden + attn @ Wo   -> d_out (f32)
  gemm128<2><<<dim3(DM / 128, NT / 128), 256, 0, stream>>>(attn, Wo_t, out, hidden, NT, DM, DM);
  // 12. h2 = rmsnorm(x, ln2)
  rms_kernel<float><<<NT, 256, 0, stream>>>(out, h2, ln2, DM, DM);
  // 13. gbuf = silu(h2@Wg) * (h2@Wu)
  gemm128<0><<<dim3(DFF / 128, NT / 128), 256, 0, stream>>>(h2, Wg_t, gbuf, nullptr, NT, DFF, DM);
  gemm128<0><<<dim3(DFF / 128, NT / 128), 256, 0, stream>>>(h2, Wu_t, ubuf, nullptr, NT, DFF, DM);
  silumul_kernel<<<(NT * DFF / 8 + 255) / 256, 256, 0, stream>>>(gbuf, ubuf, gbuf, NT * DFF / 8);
  // 14. out = x + gbuf @ Wdown
  gemm128<2><<<dim3(DM / 128, NT / 128), 256, 0, stream>>>(gbuf, Wd_t, out, out, NT, DM, DFF);

  (void)in_sizes; (void)n_in; (void)out_size; (void)ws_size;
}

// Round 4
// 1470.919 us; speedup vs baseline: 3.6396x; 1.0644x over previous
//
#include <hip/hip_runtime.h>
#include <hip/hip_bf16.h>
#include <stdint.h>

// ---------------- problem constants ----------------
#define B_    2
#define S_    2048
#define H_    16
#define DM    2048
#define QL    1536
#define KVL   512
#define NOPE_ 128
#define ROPE_ 64
#define DQK   192
#define DV    128
#define DFF   8192
#define NT    (B_ * S_)          // 4096 token rows
#define EPS_  1e-5f
#define KVLP  640                // padded kv_lr row stride (640 = 5*128)

typedef __bf16 bf16x8 __attribute__((ext_vector_type(8)));
typedef float  f32x4  __attribute__((ext_vector_type(4)));

__device__ __forceinline__ unsigned short f2bf(float f) {
  union { float f; uint32_t u; } v; v.f = f;
  uint32_t r = v.u + 0x7fffu + ((v.u >> 16) & 1u);
  return (unsigned short)(r >> 16);
}
__device__ __forceinline__ float bf2f(unsigned short h) {
  union { uint32_t u; float f; } v; v.u = ((uint32_t)h) << 16;
  return v.f;
}
__device__ __forceinline__ float ldv(float x) { return x; }
__device__ __forceinline__ float ldv(unsigned short x) { return bf2f(x); }

// async global->LDS, 16B per lane; LDS dest = wave-uniform base + lane*16
__device__ __forceinline__ void g2l16(const unsigned short* g, unsigned short* l) {
  __builtin_amdgcn_global_load_lds((const __attribute__((address_space(1))) unsigned int*)g,
                                   (__attribute__((address_space(3))) unsigned int*)l,
                                   16, 0, 0);
}

// ---------------- weight transpose + bf16 convert: W(K,N) f32 -> Wt(N,K) bf16 ----------------
__global__ __launch_bounds__(256) void wt_kernel(const float* __restrict__ W,
                                                 unsigned short* __restrict__ Wt,
                                                 int K, int N) {
  __shared__ unsigned short tile[32][33];
  int kt = blockIdx.y * 32, nt = blockIdx.x * 32;
  int tx = threadIdx.x & 31, ty = threadIdx.x >> 5;   // ty 0..7
#pragma unroll
  for (int kk = 0; kk < 32; kk += 8)
    tile[kk + ty][tx] = f2bf(W[(size_t)(kt + kk + ty) * N + nt + tx]);   // coalesced in n
  __syncthreads();
#pragma unroll
  for (int nn = 0; nn < 32; nn += 8)
    Wt[(size_t)(nt + nn + ty) * K + kt + tx] = tile[tx][nn + ty];        // coalesced in k
}

// ---------------- RMSNorm: rows x D (row stride ldin), optional weight, out bf16 ----------------
template <typename TIN>
__global__ __launch_bounds__(256) void rms_kernel(const TIN* __restrict__ in,
                                                  unsigned short* __restrict__ out,
                                                  const float* __restrict__ w,
                                                  int D, int ldin) {
  int row = blockIdx.x, tid = threadIdx.x;
  const TIN* rp = in + (size_t)row * ldin;
  float ss = 0.f;
  for (int i = tid; i < D; i += 256) { float v = ldv(rp[i]); ss += v * v; }
#pragma unroll
  for (int off = 32; off >= 1; off >>= 1) ss += __shfl_xor(ss, off);
  __shared__ float red[4];
  if ((tid & 63) == 0) red[tid >> 6] = ss;
  __syncthreads();
  ss = red[0] + red[1] + red[2] + red[3];
  float rs = rsqrtf(ss / (float)D + EPS_);
  unsigned short* op = out + (size_t)row * D;
  for (int i = tid; i < D; i += 256) {
    float v = ldv(rp[i]) * rs;
    if (w) v *= w[i];
    op[i] = f2bf(v);
  }
}

// ---------------- tiled bf16 MFMA GEMM, double-buffered: C(M,N) = A(M,K) @ Bt(N,K)^T ----------------
// block 256 = 4 waves (2x2), block tile 128x128, wave tile 64x64 (4x4 MFMA 16x16x32), BK=32
// Double-buffered LDS (2x 8KB per operand): prefetch tile k+1 after the single barrier,
// compute tile k in between -> vmcnt drain overlaps compute.
// MODE 0: store bf16   MODE 1: store f32   MODE 2: store f32 = aux(f32) + acc
// MODE 3: store bf16 = silu(aux(bf16)) * acc   (in-place safe: reads/writes same idx)
template <int MODE>
__global__ __launch_bounds__(256) void gemm128(const unsigned short* __restrict__ A,
                                               const unsigned short* __restrict__ Bt,
                                               void* C, const void* __restrict__ aux,
                                               int M, int N, int K) {
  __shared__ unsigned short As[2][128 * 32];
  __shared__ unsigned short Bs[2][128 * 32];
  int tid = threadIdx.x, lane = tid & 63, wave = tid >> 6;
  int quad = lane >> 4, l16 = lane & 15;
  int wm = wave >> 1, wn = wave & 1;
  int m0 = blockIdx.y * 128, n0 = blockIdx.x * 128;

  // staging map: flat elem f = tid*8; row = f/32, col = f%32 (two 64-row halves per operand)
  int f0 = tid * 8;
  int rs0 = f0 >> 5, cs0 = f0 & 31;
  const unsigned short* Ag0 = A + (size_t)(m0 + rs0) * K + cs0;
  const unsigned short* Ag1 = A + (size_t)(m0 + 64 + rs0) * K + cs0;
  const unsigned short* Bg0 = Bt + (size_t)(n0 + rs0) * K + cs0;
  const unsigned short* Bg1 = Bt + (size_t)(n0 + 64 + rs0) * K + cs0;

  // prologue: stage tile 0 into buffer 0
  g2l16(Ag0, As[0] + f0);
  g2l16(Ag1, As[0] + 2048 + f0);
  g2l16(Bg0, Bs[0] + f0);
  g2l16(Bg1, Bs[0] + 2048 + f0);

  f32x4 ac[4][4] = {};
  int p = 0;
  for (int k = 0; k < K; k += 32) {
    __syncthreads();   // tile k resident (compiler emits vmcnt drain); buf p^1 free for prefetch
    int k2 = k + 32;
    if (k2 < K) {      // wave-uniform branch
      g2l16(Ag0 + k2, As[p ^ 1] + f0);
      g2l16(Ag1 + k2, As[p ^ 1] + 2048 + f0);
      g2l16(Bg0 + k2, Bs[p ^ 1] + f0);
      g2l16(Bg1 + k2, Bs[p ^ 1] + 2048 + f0);
    }
    const unsigned short* ArdBase = As[p] + quad * 8 + (wm * 64 + l16) * 32;
    const unsigned short* BrdBase = Bs[p] + quad * 8 + (wn * 64 + l16) * 32;
    bf16x8 af[4], bfr[4];
#pragma unroll
    for (int mt = 0; mt < 4; ++mt) af[mt]  = *(const bf16x8*)(ArdBase + mt * 16 * 32);
#pragma unroll
    for (int nt = 0; nt < 4; ++nt) bfr[nt] = *(const bf16x8*)(BrdBase + nt * 16 * 32);
#pragma unroll
    for (int mt = 0; mt < 4; ++mt)
#pragma unroll
      for (int nt = 0; nt < 4; ++nt)
        ac[mt][nt] = __builtin_amdgcn_mfma_f32_16x16x32_bf16(af[mt], bfr[nt], ac[mt][nt], 0, 0, 0);
    p ^= 1;
  }

#pragma unroll
  for (int mt = 0; mt < 4; ++mt)
#pragma unroll
    for (int nt = 0; nt < 4; ++nt)
#pragma unroll
      for (int r = 0; r < 4; ++r) {
        int row = m0 + wm * 64 + mt * 16 + quad * 4 + r;
        int col = n0 + wn * 64 + nt * 16 + l16;
        size_t idx = (size_t)row * N + col;
        float v = ac[mt][nt][r];
        if (MODE == 0)      ((unsigned short*)C)[idx] = f2bf(v);
        else if (MODE == 1) ((float*)C)[idx] = v;
        else if (MODE == 2) ((float*)C)[idx] = ((const float*)aux)[idx] + v;
        else {
          float g = bf2f(((const unsigned short*)aux)[idx]);
          float s = g / (1.f + __expf(-g));
          ((unsigned short*)C)[idx] = f2bf(s * v);
        }
      }
}

// ---------------- build Q with RoPE, PRE-SCALED by 1/sqrt(192) ----------------
__global__ __launch_bounds__(256) void build_q_kernel(const unsigned short* __restrict__ qg,
                                                      const float* __restrict__ fcos,
                                                      const float* __restrict__ fsin,
                                                      unsigned short* __restrict__ qo) {
  const float SCALE = 0.07216878364870323f;
  int idx = blockIdx.x * 256 + threadIdx.x;
  if (idx >= NT * H_ * 96) return;
  int i = idx % 96, t = idx / 96;
  int h = t % H_, bs = t / H_, s = bs % S_;
  const unsigned short* src = qg + (size_t)bs * (H_ * DQK) + h * DQK;
  unsigned short* dst = qo + ((size_t)bs * H_ + h) * DQK;
  if (i < 32) {
    float xr = bf2f(src[NOPE_ + 2 * i]), xi = bf2f(src[NOPE_ + 2 * i + 1]);
    float c = fcos[s * 32 + i], sn = fsin[s * 32 + i];
    dst[2 * i]     = f2bf((xr * c - xi * sn) * SCALE);
    dst[2 * i + 1] = f2bf((xr * sn + xi * c) * SCALE);
  } else {
    int j = i - 32;
    dst[ROPE_ + 2 * j]     = f2bf(bf2f(src[2 * j]) * SCALE);
    dst[ROPE_ + 2 * j + 1] = f2bf(bf2f(src[2 * j + 1]) * SCALE);
  }
}

// ---------------- build K: rope(kv_lr[:,512:576]) broadcast + k_nope from kv ----------------
__global__ __launch_bounds__(256) void build_k_kernel(const float* __restrict__ kvlr,
                                                      const unsigned short* __restrict__ kv,
                                                      const float* __restrict__ fcos,
                                                      const float* __restrict__ fsin,
                                                      unsigned short* __restrict__ ko) {
  int idx = blockIdx.x * 256 + threadIdx.x;
  if (idx >= NT * H_ * 96) return;
  int i = idx % 96, t = idx / 96;
  int h = t % H_, bs = t / H_, s = bs % S_;
  unsigned short* dst = ko + ((size_t)bs * H_ + h) * DQK;
  if (i < 32) {
    float xr = kvlr[(size_t)bs * KVLP + KVL + 2 * i];
    float xi = kvlr[(size_t)bs * KVLP + KVL + 2 * i + 1];
    float c = fcos[s * 32 + i], sn = fsin[s * 32 + i];
    dst[2 * i]     = f2bf(xr * c - xi * sn);
    dst[2 * i + 1] = f2bf(xr * sn + xi * c);
  } else {
    int j = i - 32;
    dst[ROPE_ + 2 * j]     = kv[(size_t)bs * 4096 + h * DV + 2 * j];
    dst[ROPE_ + 2 * j + 1] = kv[(size_t)bs * 4096 + h * DV + 2 * j + 1];
  }
}

// ---------------- global V transpose: kv[bs][2048 + h*128 + d] -> vt[bh][d][s] ----------------
__global__ __launch_bounds__(256) void vt_kernel(const unsigned short* __restrict__ kv,
                                                 unsigned short* __restrict__ vt) {
  __shared__ unsigned short t[32][33];
  int bh = blockIdx.z, b = bh >> 4, h = bh & 15;
  int s0 = blockIdx.x * 32, d0 = blockIdx.y * 32;
  int tx = threadIdx.x & 31, ty = threadIdx.x >> 5;
#pragma unroll
  for (int i = 0; i < 32; i += 8)
    t[i + ty][tx] = kv[(size_t)(b * S_ + s0 + i + ty) * 4096 + 2048 + h * 128 + d0 + tx];
  __syncthreads();
#pragma unroll
  for (int i = 0; i < 32; i += 8)
    vt[((size_t)bh * 128 + d0 + i + ty) * S_ + s0 + tx] = t[tx][i + ty];
}

// ---------------- flash attention v2 ----------------
// Br=128 (4 waves x 32 rows), Bc=32. Q fragments in registers (pre-scaled).
// LDS strides padded: K 200, V^T 40, P 40 elems (uniform bank spread, 16B-aligned rows).
#define KSTR 200
#define VSTR 40
#define PSTR 40
__global__ __launch_bounds__(256, 2) void attn2_kernel(const unsigned short* __restrict__ Q,
                                                       const unsigned short* __restrict__ Kt,
                                                       const unsigned short* __restrict__ Vt,
                                                       const int* __restrict__ smaskg,
                                                       unsigned short* __restrict__ O) {
  __shared__ unsigned short Ks[32 * KSTR];   // 12800 B
  __shared__ unsigned short Vts[128 * VSTR]; // 10240 B
  __shared__ unsigned short Ps[4][32 * PSTR];// 10240 B
  __shared__ int smaskl[32];

  int tid = threadIdx.x, wave = tid >> 6, lane = tid & 63;
  int quad = lane >> 4, l16 = lane & 15;
  int bh = blockIdx.y, b = bh >> 4, h = bh & 15;
  int qb = (int)gridDim.x - 1 - (int)blockIdx.x;   // heavy blocks dispatch first
  int r0 = qb * 128;

  // Q fragments in registers (2 m-tiles x 6 k-steps)
  bf16x8 qf[2][6];
#pragma unroll
  for (int mt = 0; mt < 2; ++mt) {
    int rg = r0 + wave * 32 + mt * 16 + l16;
    const unsigned short* qp = Q + ((size_t)(b * S_ + rg) * H_ + h) * DQK + quad * 8;
#pragma unroll
    for (int kk = 0; kk < 6; ++kk)
      qf[mt][kk] = *(const bf16x8*)(qp + kk * 32);
  }

  float m_[2][4], l_[2][4];
  f32x4 o_[2][8] = {};
#pragma unroll
  for (int mt = 0; mt < 2; ++mt)
#pragma unroll
    for (int r = 0; r < 4; ++r) { m_[mt][r] = -3e38f; l_[mt][r] = 0.f; }

  int ktend = 4 * qb + 4;
  for (int kt = 0; kt < ktend; ++kt) {
    int j0 = kt * 32;
    __syncthreads();
#pragma unroll
    for (int i = 0; i < 3; ++i) {
      int c = tid + i * 256;
      int row = c / 24, cc = (c % 24) * 8;
      *(uint4*)(Ks + row * KSTR + cc) =
          *(const uint4*)(Kt + ((size_t)(b * S_ + j0 + row) * H_ + h) * DQK + cc);
    }
#pragma unroll
    for (int i = 0; i < 2; ++i) {
      int c = tid + i * 256;
      int d = c >> 2, cc = (c & 3) * 8;
      *(uint4*)(Vts + d * VSTR + cc) =
          *(const uint4*)(Vt + ((size_t)bh * 128 + d) * S_ + j0 + cc);
    }
    if (tid < 32) smaskl[tid] = smaskg[b * S_ + j0 + tid];
    __syncthreads();

    // S = Q K^T  (2 m-tiles x 2 n-tiles)
    f32x4 sc[2][2] = {};
#pragma unroll
    for (int kk = 0; kk < 6; ++kk) {
      bf16x8 b0 = *(const bf16x8*)(Ks + l16 * KSTR + kk * 32 + quad * 8);
      bf16x8 b1 = *(const bf16x8*)(Ks + (16 + l16) * KSTR + kk * 32 + quad * 8);
#pragma unroll
      for (int mt = 0; mt < 2; ++mt) {
        sc[mt][0] = __builtin_amdgcn_mfma_f32_16x16x32_bf16(qf[mt][kk], b0, sc[mt][0], 0, 0, 0);
        sc[mt][1] = __builtin_amdgcn_mfma_f32_16x16x32_bf16(qf[mt][kk], b1, sc[mt][1], 0, 0, 0);
      }
    }

    bool ok0 = smaskl[l16] != 0, ok1 = smaskl[16 + l16] != 0;
    int c0 = j0 + l16, c1 = j0 + 16 + l16;
#pragma unroll
    for (int mt = 0; mt < 2; ++mt) {
      int rbase = r0 + wave * 32 + mt * 16 + quad * 4;
#pragma unroll
      for (int r = 0; r < 4; ++r) {
        int rg = rbase + r;
        float s0 = (ok0 && c0 <= rg) ? sc[mt][0][r] : -1e30f;
        float s1 = (ok1 && c1 <= rg) ? sc[mt][1][r] : -1e30f;
        float tm = fmaxf(s0, s1);
        tm = fmaxf(tm, __shfl_xor(tm, 1));
        tm = fmaxf(tm, __shfl_xor(tm, 2));
        tm = fmaxf(tm, __shfl_xor(tm, 4));
        tm = fmaxf(tm, __shfl_xor(tm, 8));
        float mn = fmaxf(m_[mt][r], tm);
        float al = __expf(m_[mt][r] - mn);
        m_[mt][r] = mn;
        float p0 = __expf(s0 - mn);
        float p1 = __expf(s1 - mn);
        float ps = p0 + p1;
        ps += __shfl_xor(ps, 1);
        ps += __shfl_xor(ps, 2);
        ps += __shfl_xor(ps, 4);
        ps += __shfl_xor(ps, 8);
        l_[mt][r] = l_[mt][r] * al + ps;
#pragma unroll
        for (int nt = 0; nt < 8; ++nt) o_[mt][nt][r] *= al;
        int prow = mt * 16 + quad * 4 + r;
        Ps[wave][prow * PSTR + l16]      = f2bf(p0);
        Ps[wave][prow * PSTR + 16 + l16] = f2bf(p1);
      }
    }

    // O += P V  (A = P from per-wave LDS, B = V^T rows)
    bf16x8 pa[2];
#pragma unroll
    for (int mt = 0; mt < 2; ++mt)
      pa[mt] = *(const bf16x8*)(&Ps[wave][(mt * 16 + l16) * PSTR + quad * 8]);
#pragma unroll
    for (int nt = 0; nt < 8; ++nt) {
      bf16x8 vb = *(const bf16x8*)(Vts + (nt * 16 + l16) * VSTR + quad * 8);
#pragma unroll
      for (int mt = 0; mt < 2; ++mt)
        o_[mt][nt] = __builtin_amdgcn_mfma_f32_16x16x32_bf16(pa[mt], vb, o_[mt][nt], 0, 0, 0);
    }
  }

  // epilogue: O layout (B,S,H,DV)
#pragma unroll
  for (int mt = 0; mt < 2; ++mt)
#pragma unroll
    for (int nt = 0; nt < 8; ++nt)
#pragma unroll
      for (int r = 0; r < 4; ++r) {
        int rg = r0 + wave * 32 + mt * 16 + quad * 4 + r;
        float v = o_[mt][nt][r] / l_[mt][r];
        O[((size_t)(b * S_ + rg) * H_ + h) * DV + nt * 16 + l16] = f2bf(v);
      }
}

// ---------------- host launch ----------------
extern "C" void kernel_launch(void* const* d_in, const int* in_sizes, int n_in,
                              void* d_out, int out_size, void* d_ws, size_t ws_size,
                              hipStream_t stream) {
  const float* hidden  = (const float*)d_in[0];
  const int*   seqmask = (const int*)d_in[1];
  const float* fcos    = (const float*)d_in[2];
  const float* fsin    = (const float*)d_in[3];
  const float* ln1     = (const float*)d_in[4];
  const float* ln2     = (const float*)d_in[5];
  const float* Wqd     = (const float*)d_in[6];
  const float* Wqu     = (const float*)d_in[7];
  const float* Wkvd    = (const float*)d_in[8];
  const float* Wkvu    = (const float*)d_in[9];
  const float* Wo      = (const float*)d_in[10];
  const float* Wg      = (const float*)d_in[11];
  const float* Wu      = (const float*)d_in[12];
  const float* Wd      = (const float*)d_in[13];
  float* out = (float*)d_out;
  char* ws = (char*)d_ws;

  // weight arena (bf16, transposed N x K); Wkvd_t padded to 640 rows (rows 576+ unused)
  size_t off = 0;
  unsigned short* Wqd_t  = (unsigned short*)(ws + off); off += (size_t)QL * DM * 2;
  unsigned short* Wqu_t  = (unsigned short*)(ws + off); off += (size_t)(H_ * DQK) * QL * 2;
  unsigned short* Wkvd_t = (unsigned short*)(ws + off); off += (size_t)KVLP * DM * 2;
  unsigned short* Wkvu_t = (unsigned short*)(ws + off); off += (size_t)4096 * KVL * 2;
  unsigned short* Wo_t   = (unsigned short*)(ws + off); off += (size_t)DM * DM * 2;
  unsigned short* Wg_t   = (unsigned short*)(ws + off); off += (size_t)DFF * DM * 2;
  unsigned short* Wu_t   = (unsigned short*)(ws + off); off += (size_t)DFF * DM * 2;
  unsigned short* Wd_t   = (unsigned short*)(ws + off); off += (size_t)DM * DFF * 2;
  char* scr = ws + off;

  // scratch arena (manually aliased)
  unsigned short* h_bf   = (unsigned short*)(scr + 0);           // 16.8 MB
  unsigned short* qdown  = (unsigned short*)(scr + 16777216);    // 12.6 MB
  float*          kvlr   = (float*)(scr + 29360128);             // 10.5 MB (stride 640 f32)
  unsigned short* qlat   = (unsigned short*)(scr + 0);           // reuses h (dead after step 3)
  unsigned short* qgemm  = (unsigned short*)(scr + 39845888);    // 25.2 MB
  unsigned short* kvnorm = (unsigned short*)(scr + 65011712);    // 4.2 MB
  unsigned short* kv     = (unsigned short*)(scr + 69206016);    // 33.6 MB
  unsigned short* qattn  = (unsigned short*)(scr + 0);           // reuses h/qdown/qlat
  unsigned short* kattn  = (unsigned short*)(scr + 39845888);    // reuses qgemm (dead)
  unsigned short* attn   = (unsigned short*)(scr + 102760448);   // 16.8 MB
  unsigned short* vt     = (unsigned short*)(scr + 119537664);   // 16.8 MB
  unsigned short* h2     = (unsigned short*)(scr + 0);
  unsigned short* gbuf   = (unsigned short*)(scr + 16777216);    // 67.1 MB

  auto T = [&](const float* W, unsigned short* Wt, int K, int N) {
    wt_kernel<<<dim3(N / 32, K / 32), 256, 0, stream>>>(W, Wt, K, N);
  };
  T(Wqd, Wqd_t, DM, QL);
  T(Wqu, Wqu_t, QL, H_ * DQK);
  T(Wkvd, Wkvd_t, DM, KVL + ROPE_);    // fills rows 0..575; 576..639 garbage (unread outputs)
  T(Wkvu, Wkvu_t, KVL, 4096);
  T(Wo, Wo_t, DM, DM);
  T(Wg, Wg_t, DM, DFF);
  T(Wu, Wu_t, DM, DFF);
  T(Wd, Wd_t, DFF, DM);

  // 1. h = rmsnorm(hidden, ln1)
  rms_kernel<float><<<NT, 256, 0, stream>>>(hidden, h_bf, ln1, DM, DM);
  // 2. qdown = h @ Wq_down
  gemm128<0><<<dim3(QL / 128, NT / 128), 256, 0, stream>>>(h_bf, Wqd_t, qdown, nullptr, NT, QL, DM);
  // 3. kvlr = h @ Wkv_down (f32, N padded to 640)
  gemm128<1><<<dim3(KVLP / 128, NT / 128), 256, 0, stream>>>(h_bf, Wkvd_t, kvlr, nullptr, NT, KVLP, DM);
  // 4. qlat = rmsnorm(qdown)
  rms_kernel<unsigned short><<<NT, 256, 0, stream>>>(qdown, qlat, nullptr, QL, QL);
  // 5. qgemm = qlat @ Wq_up
  gemm128<0><<<dim3(H_ * DQK / 128, NT / 128), 256, 0, stream>>>(qlat, Wqu_t, qgemm, nullptr, NT, H_ * DQK, QL);
  // 6. kvnorm = rmsnorm(kvlr[:, :512])
  rms_kernel<float><<<NT, 256, 0, stream>>>(kvlr, kvnorm, nullptr, KVL, KVLP);
  // 7. kv = kvnorm @ Wkv_up
  gemm128<0><<<dim3(4096 / 128, NT / 128), 256, 0, stream>>>(kvnorm, Wkvu_t, kv, nullptr, NT, 4096, KVL);
  // 8/9. assemble Q (pre-scaled) and K with RoPE; transpose V globally
  int nbq = (NT * H_ * 96 + 255) / 256;
  build_q_kernel<<<nbq, 256, 0, stream>>>(qgemm, fcos, fsin, qattn);
  build_k_kernel<<<nbq, 256, 0, stream>>>(kvlr, kv, fcos, fsin, kattn);
  vt_kernel<<<dim3(S_ / 32, DV / 32, B_ * H_), 256, 0, stream>>>(kv, vt);
  // 10. attention
  attn2_kernel<<<dim3(S_ / 128, B_ * H_), 256, 0, stream>>>(qattn, kattn, vt, seqmask, attn);
  // 11. x = hidden + attn @ Wo   -> d_out (f32)
  gemm128<2><<<dim3(DM / 128, NT / 128), 256, 0, stream>>>(attn, Wo_t, out, hidden, NT, DM, DM);
  // 12. h2 = rmsnorm(x, ln2)
  rms_kernel<float><<<NT, 256, 0, stream>>>(out, h2, ln2, DM, DM);
  // 13. gbuf = h2@Wg ; gbuf = silu(gbuf) * (h2@Wu)  (MODE 3 epilogue fusion, in-place)
  gemm128<0><<<dim3(DFF / 128, NT / 128), 256, 0, stream>>>(h2, Wg_t, gbuf, nullptr, NT, DFF, DM);
  gemm128<3><<<dim3(DFF / 128, NT / 128), 256, 0, stream>>>(h2, Wu_t, gbuf, gbuf, NT, DFF, DM);
  // 14. out = x + gbuf @ Wdown
  gemm128<2><<<dim3(DM / 128, NT / 128), 256, 0, stream>>>(gbuf, Wd_t, out, out, NT, DM, DFF);

  (void)in_sizes; (void)n_in; (void)out_size; (void)ws_size;
}